// Round 7
// baseline (1755.946 us; speedup 1.0000x reference)
//
#include <hip/hip_runtime.h>

// ---------------------------------------------------------------------------
// MoE Autoencoder, MI355X (gfx950). DTYPE-ADAPTIVE (f32 or bf16 inputs).
// R7 changes vs R6 (1532us):
//  - rescue_partial was STILL 289us == R5: WRITE_SIZE 433KB revealed
//    acnt ~ 850 rows (not ~7). Both variants streamed acnt x 8MB = 6.9GB of
//    encW through L2/L3 at the ~24TB/s cache ceiling. Fix is W-REUSE:
//    rescue_tile processes 8 amb rows per block (x rows staged in LDS,
//    W-slice read once for all 8) -> traffic / 8.
//  - TAU 8e-3 -> 3e-3: cheap-pass gap-error RMS ~ 4e-4, so 3e-3 is still
//    ~7 sigma; rescue population ~850 -> ~320.
//  - Everything else identical to R6 (BK=64 swizzled GEMMs etc).
// ---------------------------------------------------------------------------

#define N_TOK 16384
#define IN_DIM 1024
#define HID 2048
#define NEXP 8
#define TAU 3.0e-3f
#define RROWS 8

typedef __bf16 bf16_t;
typedef __bf16 bf16x8 __attribute__((ext_vector_type(8)));
typedef __bf16 bf16x4v __attribute__((ext_vector_type(4)));
typedef float f32x4 __attribute__((ext_vector_type(4)));
typedef unsigned short ushort_t;

#define CLAMP1E4(v) fmaxf(fminf((v), 1.0e4f), -1.0e4f)

#define ASYNC16(gp, lp)                                                        \
  __builtin_amdgcn_global_load_lds(                                            \
      (const __attribute__((address_space(1))) void*)(gp),                     \
      (__attribute__((address_space(3))) void*)(lp), 16, 0, 0)

static __device__ inline ushort_t b2u(bf16_t v) {
  union { bf16_t b; ushort_t u; } x; x.b = v; return x.u;
}

// ---------------------------------------------------------------------------
__global__ __launch_bounds__(256) void fill_bf16(bf16_t* __restrict__ p,
                                                 float v, int n) {
  const int i = blockIdx.x * 256 + threadIdx.x;
  if (i < n) p[i] = (bf16_t)v;
}

// ---------------------------------------------------------------------------
// flag=1  <=>  raw data is f32 (reading it as bf16 yields wild exponents)
// ---------------------------------------------------------------------------
__global__ __launch_bounds__(256) void detect_dtype(
    const ushort_t* __restrict__ xr, int* __restrict__ flag) {
  __shared__ int s_bad;
  if (threadIdx.x == 0) s_bad = 0;
  __syncthreads();
  int bad = 0;
  for (int i = threadIdx.x; i < 4096; i += 256) {
    const int e = (xr[i] >> 7) & 0xFF;
    if (e >= 0xC0) bad = 1;  // |v| >= 2^65: impossible for real bf16 data
  }
  if (__any(bad) && (threadIdx.x & 63) == 0) atomicOr(&s_bad, 1);
  __syncthreads();
  if (threadIdx.x == 0) *flag = s_bad;
}

// ---------------------------------------------------------------------------
// vectorized x4 conversion for the big x buffer
__global__ __launch_bounds__(256) void cvt_to_bf16_x4(
    const void* __restrict__ src, bf16_t* __restrict__ dst, int n4,
    const int* __restrict__ flagp) {
  const int f = *flagp;
  const int i = blockIdx.x * 256 + threadIdx.x;
  if (i >= n4) return;
  bf16x4v o;
  if (f) {
    const f32x4 v = ((const f32x4*)src)[i];
    o[0] = (bf16_t)v[0]; o[1] = (bf16_t)v[1];
    o[2] = (bf16_t)v[2]; o[3] = (bf16_t)v[3];
  } else {
    o = ((const bf16x4v*)src)[i];
  }
  ((bf16x4v*)dst)[i] = o;
}

// ---------------------------------------------------------------------------
// all small conversions in one launch. blockIdx.y = segment.
// ---------------------------------------------------------------------------
__global__ __launch_bounds__(256) void cvt_small(
    const void* __restrict__ encB, const void* __restrict__ expB,
    const void* __restrict__ resB, const void* __restrict__ decB,
    const void* __restrict__ coefB, const void* __restrict__ gateW,
    const void* __restrict__ coefW, float* __restrict__ encBf,
    float* __restrict__ expBf, float* __restrict__ resBf,
    float* __restrict__ decBf, float* __restrict__ coefBf,
    bf16_t* __restrict__ gWb, bf16_t* __restrict__ cWb,
    const int* __restrict__ flagp) {
  const int f = *flagp;
  const int i = blockIdx.x * 256 + threadIdx.x;
  const int seg = blockIdx.y;
  const void* src;
  int n;
  switch (seg) {
    case 0: src = encB;  n = HID; break;
    case 1: src = expB;  n = NEXP * HID; break;
    case 2: src = resB;  n = HID; break;
    case 3: src = decB;  n = IN_DIM; break;
    case 4: src = coefB; n = 2; break;
    case 5: src = gateW; n = HID * 8; break;
    default: src = coefW; n = HID * 2; break;
  }
  if (i >= n) return;
  const float v = f ? ((const float*)src)[i] : (float)((const bf16_t*)src)[i];
  switch (seg) {
    case 0: encBf[i] = v; break;
    case 1: expBf[i] = v; break;
    case 2: resBf[i] = v; break;
    case 3: decBf[i] = v; break;
    case 4: coefBf[i] = v; break;
    case 5: gWb[i] = (bf16_t)v; break;
    default: cWb[i] = (bf16_t)v; break;
  }
}

// ---------------------------------------------------------------------------
// transpose + convert: src[R][C] (f32 or bf16 per flag) -> dst[C][R] bf16.
// ---------------------------------------------------------------------------
__global__ __launch_bounds__(256) void transpose_cvt(
    const void* __restrict__ src0, ushort_t* __restrict__ dst, int R, int C,
    size_t elem_off, const int* __restrict__ flagp, size_t src_zstride,
    size_t dst_zstride) {
  __shared__ ushort_t t[32][33];
  const int f = *flagp;
  const size_t eoff = elem_off + (size_t)blockIdx.z * src_zstride;
  dst += (size_t)blockIdx.z * dst_zstride;
  const int c0 = blockIdx.x * 32, r0 = blockIdx.y * 32;
  const int tx = threadIdx.x, ty = threadIdx.y;
  if (f) {
    const float* s = (const float*)src0 + eoff;
#pragma unroll
    for (int i = 0; i < 4; ++i)
      t[ty + i * 8][tx] =
          b2u((bf16_t)s[(size_t)(r0 + ty + i * 8) * C + c0 + tx]);
  } else {
    const ushort_t* s = (const ushort_t*)src0 + eoff;
#pragma unroll
    for (int i = 0; i < 4; ++i)
      t[ty + i * 8][tx] = s[(size_t)(r0 + ty + i * 8) * C + c0 + tx];
  }
  __syncthreads();
#pragma unroll
  for (int i = 0; i < 4; ++i)
    dst[(size_t)(c0 + ty + i * 8) * R + r0 + tx] = t[tx][ty + i * 8];
}

// ---------------------------------------------------------------------------
// Shared BK=64 GEMM geometry (128x128 tile, [128][64] bf16 LDS per matrix,
// swizzled: achieved by permuting the per-lane GLOBAL source and XOR-ing the
// ds_read column. 2 K-sub-steps of 16 MFMA each.
// ---------------------------------------------------------------------------

// enc: h = relu(x @ enc_W + b) (bf16). K = IN_DIM (16 K-steps).
__global__ __launch_bounds__(256) void enc_gemm(
    const bf16_t* __restrict__ A, const bf16_t* __restrict__ Bt,
    const float* __restrict__ bias, bf16_t* __restrict__ H) {
  __shared__ bf16_t As[128 * 64];
  __shared__ bf16_t Bs[128 * 64];

  const int tid = threadIdx.x, lane = tid & 63, w = tid >> 6;
  const int wr = w >> 1, wc = w & 1, quad = lane >> 4, l16 = lane & 15;
  const int m0 = blockIdx.x * 128, n0 = blockIdx.y * 128;
  const char* Ab = (const char*)A;
  const char* Bb = (const char*)Bt;
  const size_t lda = (size_t)IN_DIM * 2;

  const f32x4 fz = {0.f, 0.f, 0.f, 0.f};
  f32x4 acc[4][4];
#pragma unroll
  for (int i = 0; i < 4; ++i)
#pragma unroll
    for (int j = 0; j < 4; ++j) acc[i][j] = fz;

  size_t aoff[4], boff[4];
  int cb[4];
#pragma unroll
  for (int c = 0; c < 4; ++c) {
    cb[c] = (w * 4 + c) * 1024;
    const int o = cb[c] + lane * 16;
    const int row = o >> 7;
    const int kb = (o & 127) ^ ((row & 7) << 4);  // pre-swizzled source
    aoff[c] = (size_t)(m0 + row) * lda + kb;
    boff[c] = (size_t)(n0 + row) * lda + kb;
  }
  const int sw = (l16 & 7) << 3;  // element-space read swizzle

  for (int kt = 0; kt < IN_DIM / 64; ++kt) {
    __syncthreads();
#pragma unroll
    for (int c = 0; c < 4; ++c) {
      ASYNC16(Ab + aoff[c] + (size_t)kt * 128, (char*)As + cb[c]);
      ASYNC16(Bb + boff[c] + (size_t)kt * 128, (char*)Bs + cb[c]);
    }
    __syncthreads();

#pragma unroll
    for (int ks = 0; ks < 2; ++ks) {
      const int co = (ks * 32 + quad * 8) ^ sw;
      bf16x8 af[4], bfr[4];
#pragma unroll
      for (int i = 0; i < 4; ++i)
        af[i] = *(const bf16x8*)&As[(wr * 64 + i * 16 + l16) * 64 + co];
#pragma unroll
      for (int j = 0; j < 4; ++j)
        bfr[j] = *(const bf16x8*)&Bs[(wc * 64 + j * 16 + l16) * 64 + co];
#pragma unroll
      for (int i = 0; i < 4; ++i)
#pragma unroll
        for (int j = 0; j < 4; ++j)
          acc[i][j] = __builtin_amdgcn_mfma_f32_16x16x32_bf16(
              af[i], bfr[j], acc[i][j], 0, 0, 0);
    }
  }

  float bj[4];
  int colj[4];
#pragma unroll
  for (int j = 0; j < 4; ++j) {
    colj[j] = n0 + wc * 64 + j * 16 + l16;
    bj[j] = bias[colj[j]];
  }

#pragma unroll
  for (int i = 0; i < 4; ++i) {
#pragma unroll
    for (int r = 0; r < 4; ++r) {
      const int row = m0 + wr * 64 + i * 16 + quad * 4 + r;
#pragma unroll
      for (int j = 0; j < 4; ++j) {
        const float v = fminf(fmaxf(acc[i][j][r] + bj[j], 0.f), 1.0e4f);
        H[(size_t)row * HID + colj[j]] = (bf16_t)v;
      }
    }
  }
}

// ---------------------------------------------------------------------------
// gate_from_h: one wave per 4 rows; gate/coef logits + softmax/argmax;
// counts per expert; ambiguous rows -> rescue list.
// ---------------------------------------------------------------------------
__global__ __launch_bounds__(256) void gate_from_h(
    const bf16_t* __restrict__ H, const bf16_t* __restrict__ gW,
    const bf16_t* __restrict__ cW, const float* __restrict__ coefBf,
    float* __restrict__ s0g, float* __restrict__ s1g, float* __restrict__ c0g,
    int* __restrict__ eidx, int* __restrict__ ambig, int* __restrict__ acnt,
    int* __restrict__ cnt) {
  const int tid = threadIdx.x, lane = tid & 63, w = tid >> 6;
  const int r0 = blockIdx.x * 16 + w * 4;  // 4 waves * 4 rows per block

  float acc[4][10];
#pragma unroll
  for (int g = 0; g < 4; ++g)
#pragma unroll
    for (int o = 0; o < 10; ++o) acc[g][o] = 0.f;

#pragma unroll
  for (int it = 0; it < HID / 512; ++it) {  // 4 iterations
    const int h0 = it * 512 + lane * 8;
    bf16x8 hv[4];
#pragma unroll
    for (int g = 0; g < 4; ++g)
      hv[g] = *(const bf16x8*)(H + (size_t)(r0 + g) * HID + h0);
    const bf16_t* gp = gW + (size_t)h0 * 8;
    const bf16_t* cp = cW + (size_t)h0 * 2;
    bf16x8 cc0 = *(const bf16x8*)(cp);
    bf16x8 cc1 = *(const bf16x8*)(cp + 8);
#pragma unroll
    for (int k = 0; k < 8; ++k) {
      const bf16x8 gk = *(const bf16x8*)(gp + k * 8);
      const float ck0 = (k < 4) ? (float)cc0[(k & 3) * 2]
                                : (float)cc1[(k & 3) * 2];
      const float ck1 = (k < 4) ? (float)cc0[(k & 3) * 2 + 1]
                                : (float)cc1[(k & 3) * 2 + 1];
#pragma unroll
      for (int g = 0; g < 4; ++g) {
        const float v = (float)hv[g][k];
#pragma unroll
        for (int o = 0; o < 8; ++o) acc[g][o] += v * (float)gk[o];
        acc[g][8] += v * ck0;
        acc[g][9] += v * ck1;
      }
    }
  }

#pragma unroll
  for (int m = 1; m < 64; m <<= 1)
#pragma unroll
    for (int g = 0; g < 4; ++g)
#pragma unroll
      for (int o = 0; o < 10; ++o) acc[g][o] += __shfl_xor(acc[g][o], m);

  if (lane == 0) {
#pragma unroll
    for (int g = 0; g < 4; ++g) {
      const int r = r0 + g;
      float lv[8];
#pragma unroll
      for (int e = 0; e < 8; ++e) lv[e] = acc[g][e];
      float mx = lv[0];
      int idx = 0;
#pragma unroll
      for (int e = 1; e < 8; ++e)
        if (lv[e] > mx) { mx = lv[e]; idx = e; }
      float s2 = -1.0e30f;
#pragma unroll
      for (int e = 0; e < 8; ++e)
        if (e != idx) s2 = fmaxf(s2, lv[e]);
      float s = 0.f;
#pragma unroll
      for (int e = 0; e < 8; ++e) s += expf(lv[e] - mx);
      const float gate = 1.f / s;
      const float c0 = acc[g][8] + coefBf[0], c1 = acc[g][9] + coefBf[1];
      const float cm = fmaxf(c0, c1);
      const float e0 = expf(c0 - cm), e1 = expf(c1 - cm);
      const float inv = 1.f / (e0 + e1);
      const float p0 = e0 * inv;
      c0g[r] = p0;
      s1g[r] = e1 * inv;
      s0g[r] = gate * p0;
      eidx[r] = idx;
      atomicAdd(&cnt[idx], 1);
      if (mx - s2 < TAU) {
        const int p = atomicAdd(acnt, 1);
        ambig[p] = r;
      }
    }
  }
}

// ---------------------------------------------------------------------------
// rescue_tile: grid (128, 8). Block (t, s) recomputes h columns
// [s*256, s*256+256) for 8 ambiguous rows ambig[t*8 .. t*8+7] in f64 from
// RAW inputs. The 8 x-rows are staged in LDS and the 1MB W-slice is read
// ONCE for all 8 rows (R6's one-row version re-streamed W per row: 6.9GB
// through L2/L3 = the 289us ceiling). Per-row fixed-order reduce ->
// pglg[(i*8+s)*8+e]. No atomics -> deterministic.
// ---------------------------------------------------------------------------
__global__ __launch_bounds__(256) void rescue_tile(
    const void* __restrict__ xraw, const void* __restrict__ encWraw,
    const float* __restrict__ encBf, const void* __restrict__ gateWraw,
    const int* __restrict__ flagp, const int* __restrict__ ambig,
    const int* __restrict__ acnt, double* __restrict__ pglg) {
  const int an0 = *acnt;
  const int an = an0 < 1024 ? an0 : 1024;  // sliced path covers first 1024
  const int i0 = blockIdx.x * RROWS;
  if (i0 >= an) return;
  int nr = an - i0;
  if (nr > RROWS) nr = RROWS;
  const int s = blockIdx.y;
  const int f = *flagp;
  const int tid = threadIdx.x;
  const int j = s * 256 + tid;  // this thread's h-column

  __shared__ int rows_sh[RROWS];
  __shared__ float xs[RROWS][IN_DIM];  // 32 KB
  if (tid < RROWS) rows_sh[tid] = ambig[i0 + (tid < nr ? tid : 0)];
  __syncthreads();

  for (int r = 0; r < RROWS; ++r) {
    const int row = rows_sh[r];
    if (f) {
      const float* xp = (const float*)xraw + (size_t)row * IN_DIM;
      for (int k = tid; k < IN_DIM; k += 256) xs[r][k] = xp[k];
    } else {
      const bf16_t* xp = (const bf16_t*)xraw + (size_t)row * IN_DIM;
      for (int k = tid; k < IN_DIM; k += 256) xs[r][k] = (float)xp[k];
    }
  }
  __syncthreads();

  double hacc[RROWS];
#pragma unroll
  for (int r = 0; r < RROWS; ++r) hacc[r] = 0.0;

  if (f) {
    const float* W = (const float*)encWraw + j;
    for (int k0 = 0; k0 < IN_DIM; k0 += 8) {
      double wd[8];
#pragma unroll
      for (int kk = 0; kk < 8; ++kk)
        wd[kk] = (double)W[(size_t)(k0 + kk) * HID];
#pragma unroll
      for (int r = 0; r < RROWS; ++r) {
        const f32x4 xa = *(const f32x4*)&xs[r][k0];
        const f32x4 xb = *(const f32x4*)&xs[r][k0 + 4];
        double a = hacc[r];
        a += (double)xa[0] * wd[0];
        a += (double)xa[1] * wd[1];
        a += (double)xa[2] * wd[2];
        a += (double)xa[3] * wd[3];
        a += (double)xb[0] * wd[4];
        a += (double)xb[1] * wd[5];
        a += (double)xb[2] * wd[6];
        a += (double)xb[3] * wd[7];
        hacc[r] = a;
      }
    }
  } else {
    const bf16_t* W = (const bf16_t*)encWraw + j;
    for (int k0 = 0; k0 < IN_DIM; k0 += 8) {
      double wd[8];
#pragma unroll
      for (int kk = 0; kk < 8; ++kk)
        wd[kk] = (double)(float)W[(size_t)(k0 + kk) * HID];
#pragma unroll
      for (int r = 0; r < RROWS; ++r) {
        const f32x4 xa = *(const f32x4*)&xs[r][k0];
        const f32x4 xb = *(const f32x4*)&xs[r][k0 + 4];
        double a = hacc[r];
        a += (double)xa[0] * wd[0];
        a += (double)xa[1] * wd[1];
        a += (double)xa[2] * wd[2];
        a += (double)xa[3] * wd[3];
        a += (double)xb[0] * wd[4];
        a += (double)xb[1] * wd[5];
        a += (double)xb[2] * wd[6];
        a += (double)xb[3] * wd[7];
        hacc[r] = a;
      }
    }
  }

  // per-column gate weights + bias (shared across the 8 rows)
  double gv[8];
  if (f) {
    const float* g = (const float*)gateWraw + (size_t)j * 8;
#pragma unroll
    for (int e = 0; e < 8; ++e) gv[e] = (double)g[e];
  } else {
    const bf16_t* g = (const bf16_t*)gateWraw + (size_t)j * 8;
#pragma unroll
    for (int e = 0; e < 8; ++e) gv[e] = (double)(float)g[e];
  }
  const double bj = (double)encBf[j];

  __shared__ double red[4][8];
  const int w = tid >> 6, lane = tid & 63;
  for (int r = 0; r < RROWS; ++r) {
    double lg[8];
    const double h = hacc[r] + bj;
#pragma unroll
    for (int e = 0; e < 8; ++e) lg[e] = (h > 0.0) ? h * gv[e] : 0.0;
#pragma unroll
    for (int m = 1; m < 64; m <<= 1)
#pragma unroll
      for (int e = 0; e < 8; ++e) lg[e] += __shfl_xor(lg[e], m);
    if (lane == 0)
#pragma unroll
      for (int e = 0; e < 8; ++e) red[w][e] = lg[e];
    __syncthreads();
    if (tid == 0 && r < nr) {
#pragma unroll
      for (int e = 0; e < 8; ++e)
        pglg[((size_t)(i0 + r) * 8 + s) * 8 + e] =
            red[0][e] + red[1][e] + red[2][e] + red[3][e];
    }
    __syncthreads();
  }
}

// ---------------------------------------------------------------------------
// rescue_final: sums the 8 slice-partials per row in FIXED order (f64),
// argmax + softmax, updates s0g/eidx/cnt.
// ---------------------------------------------------------------------------
__global__ __launch_bounds__(64) void rescue_final(
    const int* __restrict__ ambig, const int* __restrict__ acnt,
    const float* __restrict__ c0g, const double* __restrict__ pglg,
    float* __restrict__ s0g, int* __restrict__ eidx, int* __restrict__ cnt) {
  const int i = blockIdx.x;
  if (i >= *acnt || threadIdx.x != 0) return;
  const int r = ambig[i];
  double t[8];
#pragma unroll
  for (int e = 0; e < 8; ++e) {
    double a = 0.0;
#pragma unroll
    for (int s = 0; s < 8; ++s) a += pglg[((size_t)i * 8 + s) * 8 + e];
    t[e] = a;
  }
  double m = t[0];
  int idx = 0;
#pragma unroll
  for (int e = 1; e < 8; ++e)
    if (t[e] > m) { m = t[e]; idx = e; }
  double s = 0.0;
#pragma unroll
  for (int e = 0; e < 8; ++e) s += exp(t[e] - m);
  s0g[r] = (float)((1.0 / s) * (double)c0g[r]);
  const int old = eidx[r];
  if (idx != old) {
    atomicSub(&cnt[old], 1);
    atomicAdd(&cnt[idx], 1);
    eidx[r] = idx;
  }
}

// ---------------------------------------------------------------------------
// rescue_rows (legacy whole-row, ioff-based): guards the acnt>1024 overflow
// of the tiled path (normally a no-op).
// ---------------------------------------------------------------------------
__global__ __launch_bounds__(256) void rescue_rows(
    const void* __restrict__ xraw, const void* __restrict__ encWraw,
    const float* __restrict__ encBf, const void* __restrict__ gateWraw,
    const int* __restrict__ flagp, const int* __restrict__ ambig,
    const int* __restrict__ acnt, const float* __restrict__ c0g,
    float* __restrict__ s0g, int* __restrict__ eidx, int* __restrict__ cnt,
    int ioff) {
  const int i = blockIdx.x + ioff;
  if (i >= *acnt) return;
  const int r = ambig[i];
  const int f = *flagp;
  const int tid = threadIdx.x;

  __shared__ float xs[IN_DIM];
  if (f) {
    const float* xp = (const float*)xraw + (size_t)r * IN_DIM;
    for (int k = tid; k < IN_DIM; k += 256) xs[k] = xp[k];
  } else {
    const bf16_t* xp = (const bf16_t*)xraw + (size_t)r * IN_DIM;
    for (int k = tid; k < IN_DIM; k += 256) xs[k] = (float)xp[k];
  }
  __syncthreads();

  double hacc[8] = {0, 0, 0, 0, 0, 0, 0, 0};
  if (f) {
    const float* W = (const float*)encWraw;
    for (int k0 = 0; k0 < IN_DIM; k0 += 8) {
      float wv[8][8];
#pragma unroll
      for (int kk = 0; kk < 8; ++kk) {
        const float* Wr = W + (size_t)(k0 + kk) * HID + tid;
#pragma unroll
        for (int jj = 0; jj < 8; ++jj) wv[kk][jj] = Wr[jj * 256];
      }
#pragma unroll
      for (int kk = 0; kk < 8; ++kk) {
        const double xv = (double)xs[k0 + kk];
#pragma unroll
        for (int jj = 0; jj < 8; ++jj) hacc[jj] += xv * (double)wv[kk][jj];
      }
    }
  } else {
    const bf16_t* W = (const bf16_t*)encWraw;
    for (int k0 = 0; k0 < IN_DIM; k0 += 8) {
      float wv[8][8];
#pragma unroll
      for (int kk = 0; kk < 8; ++kk) {
        const bf16_t* Wr = W + (size_t)(k0 + kk) * HID + tid;
#pragma unroll
        for (int jj = 0; jj < 8; ++jj) wv[kk][jj] = (float)Wr[jj * 256];
      }
#pragma unroll
      for (int kk = 0; kk < 8; ++kk) {
        const double xv = (double)xs[k0 + kk];
#pragma unroll
        for (int jj = 0; jj < 8; ++jj) hacc[jj] += xv * (double)wv[kk][jj];
      }
    }
  }

  double lg[8] = {0, 0, 0, 0, 0, 0, 0, 0};
#pragma unroll
  for (int jj = 0; jj < 8; ++jj) {
    const int j = tid + jj * 256;
    double h = hacc[jj] + (double)encBf[j];
    if (h > 0.0) {
      if (f) {
        const float* g = (const float*)gateWraw + (size_t)j * 8;
#pragma unroll
        for (int e = 0; e < 8; ++e) lg[e] += h * (double)g[e];
      } else {
        const bf16_t* g = (const bf16_t*)gateWraw + (size_t)j * 8;
#pragma unroll
        for (int e = 0; e < 8; ++e) lg[e] += h * (double)(float)g[e];
      }
    }
  }
#pragma unroll
  for (int m = 1; m < 64; m <<= 1)
#pragma unroll
    for (int e = 0; e < 8; ++e) lg[e] += __shfl_xor(lg[e], m);

  __shared__ double red[4][8];
  const int w = tid >> 6, lane = tid & 63;
  if (lane == 0)
#pragma unroll
    for (int e = 0; e < 8; ++e) red[w][e] = lg[e];
  __syncthreads();
  if (tid == 0) {
    double t[8];
#pragma unroll
    for (int e = 0; e < 8; ++e)
      t[e] = red[0][e] + red[1][e] + red[2][e] + red[3][e];
    double m = t[0];
    int idx = 0;
#pragma unroll
    for (int e = 1; e < 8; ++e)
      if (t[e] > m) { m = t[e]; idx = e; }
    double s = 0.0;
#pragma unroll
    for (int e = 0; e < 8; ++e) s += exp(t[e] - m);
    s0g[r] = (float)((1.0 / s) * (double)c0g[r]);
    const int old = eidx[r];
    if (idx != old) {
      atomicSub(&cnt[old], 1);
      atomicAdd(&cnt[idx], 1);
      eidx[r] = idx;
    }
  }
}

// ---------------------------------------------------------------------------
__global__ __launch_bounds__(256) void place_rows(
    const int* __restrict__ eidx, const int* __restrict__ cnt,
    int* __restrict__ curs, int* __restrict__ permflat) {
  const int r = blockIdx.x * 256 + threadIdx.x;
  const int e = eidx[r];
  int prefix = 0;
  for (int ee = 0; ee < NEXP; ++ee)
    if (ee < e) prefix += cnt[ee];
  const int pos = atomicAdd(&curs[e], 1);
  permflat[prefix + pos] = r;
}

// ---------------------------------------------------------------------------
__global__ __launch_bounds__(256) void gather_rows(
    const bf16_t* __restrict__ H, const int* __restrict__ permflat,
    const float* __restrict__ s0g, const float* __restrict__ s1g,
    bf16_t* __restrict__ Hp, int* __restrict__ rowid,
    float* __restrict__ s0p, float* __restrict__ s1p) {
  const int w = threadIdx.x >> 6, lane = threadIdx.x & 63;
  const int p = blockIdx.x * 4 + w;
  const int r = permflat[p];
  if (lane == 0) {
    rowid[p] = r;
    s0p[p] = s0g[r];
    s1p[p] = s1g[r];
  }
  const bf16x8* src = (const bf16x8*)(H + (size_t)r * HID);
  bf16x8* dst = (bf16x8*)(Hp + (size_t)p * HID);
#pragma unroll
  for (int i = 0; i < 4; ++i) dst[lane + i * 64] = src[lane + i * 64];
}

// ---------------------------------------------------------------------------
// expert_gemm_t: contiguous-A expert GEMM over Hperm, tile table from cnt[].
// BK=64 + swizzled LDS. mid[rowid] = s0 * (h @ We + be).
// ---------------------------------------------------------------------------
__global__ __launch_bounds__(256) void expert_gemm_t(
    const bf16_t* __restrict__ Hp, const bf16_t* __restrict__ wTall,
    size_t wstride, const float* __restrict__ expBf,
    const int* __restrict__ cnt, const int* __restrict__ rowid,
    const float* __restrict__ s0p, bf16_t* __restrict__ mid) {
  __shared__ bf16_t As[128 * 64];
  __shared__ bf16_t Bs[128 * 64];
  __shared__ int rows_s[128];
  __shared__ float s0_s[128];

  // tile table on the fly: x -> (expert e, tile t)
  const int x = blockIdx.x;
  int e = -1, base = 0, nrows = 0;
  {
    int acc = 0, pre = 0;
    for (int ee = 0; ee < NEXP; ++ee) {
      const int ce = cnt[ee];
      const int nt = (ce + 127) >> 7;
      if (x < acc + nt) {
        const int t = x - acc;
        e = ee;
        base = pre + t * 128;
        nrows = ce - t * 128;
        if (nrows > 128) nrows = 128;
        break;
      }
      acc += nt;
      pre += ce;
    }
  }
  if (e < 0) return;

  const int tid = threadIdx.x, lane = tid & 63, w = tid >> 6;
  const int wr = w >> 1, wc = w & 1, quad = lane >> 4, l16 = lane & 15;

  if (tid < 128) {
    int grow = -1;
    float a0 = 0.f;
    if (tid < nrows) {
      grow = rowid[base + tid];
      a0 = s0p[base + tid];
    }
    rows_s[tid] = grow;
    s0_s[tid] = a0;
  }
  __syncthreads();

  const int n0 = blockIdx.y * 128;
  const char* Hb = (const char*)Hp;
  const char* Wb = (const char*)(wTall + (size_t)e * wstride);

  size_t aoff[4], boff[4];
  int cb[4];
#pragma unroll
  for (int c = 0; c < 4; ++c) {
    cb[c] = (w * 4 + c) * 1024;
    const int o = cb[c] + lane * 16;
    const int row = o >> 7;
    const int kb = (o & 127) ^ ((row & 7) << 4);
    int ar = base + row;
    if (ar > N_TOK - 1) ar = N_TOK - 1;  // tail-tile clamp (masked at write)
    aoff[c] = (size_t)ar * (HID * 2) + kb;
    boff[c] = (size_t)(n0 + row) * (HID * 2) + kb;
  }
  const int sw = (l16 & 7) << 3;

  const f32x4 fz = {0.f, 0.f, 0.f, 0.f};
  f32x4 acc[4][4];
#pragma unroll
  for (int i = 0; i < 4; ++i)
#pragma unroll
    for (int j = 0; j < 4; ++j) acc[i][j] = fz;

  for (int kt = 0; kt < HID / 64; ++kt) {
    __syncthreads();
#pragma unroll
    for (int c = 0; c < 4; ++c) {
      ASYNC16(Hb + aoff[c] + (size_t)kt * 128, (char*)As + cb[c]);
      ASYNC16(Wb + boff[c] + (size_t)kt * 128, (char*)Bs + cb[c]);
    }
    __syncthreads();

#pragma unroll
    for (int ks = 0; ks < 2; ++ks) {
      const int co = (ks * 32 + quad * 8) ^ sw;
      bf16x8 af[4], bfr[4];
#pragma unroll
      for (int i = 0; i < 4; ++i)
        af[i] = *(const bf16x8*)&As[(wr * 64 + i * 16 + l16) * 64 + co];
#pragma unroll
      for (int j = 0; j < 4; ++j)
        bfr[j] = *(const bf16x8*)&Bs[(wc * 64 + j * 16 + l16) * 64 + co];
#pragma unroll
      for (int i = 0; i < 4; ++i)
#pragma unroll
        for (int j = 0; j < 4; ++j)
          acc[i][j] = __builtin_amdgcn_mfma_f32_16x16x32_bf16(
              af[i], bfr[j], acc[i][j], 0, 0, 0);
    }
  }

  const float* eBe = expBf + (size_t)e * HID;
  float beb[4];
  int colj[4];
#pragma unroll
  for (int j = 0; j < 4; ++j) {
    colj[j] = n0 + wc * 64 + j * 16 + l16;
    beb[j] = eBe[colj[j]];
  }
#pragma unroll
  for (int i = 0; i < 4; ++i) {
#pragma unroll
    for (int r = 0; r < 4; ++r) {
      const int lr = wr * 64 + i * 16 + quad * 4 + r;
      const int grow = rows_s[lr];
      if (grow < 0) continue;
      const float s0 = s0_s[lr];
#pragma unroll
      for (int j = 0; j < 4; ++j) {
        const float v = CLAMP1E4(s0 * (acc[i][j][r] + beb[j]));
        mid[(size_t)grow * HID + colj[j]] = (bf16_t)v;
      }
    }
  }
}

// ---------------------------------------------------------------------------
// res_gemm_p: reads Hperm (contiguous), RMW-scatters into mid[rowid].
// BK=64 + swizzled LDS.
// ---------------------------------------------------------------------------
__global__ __launch_bounds__(256) void res_gemm_p(
    const bf16_t* __restrict__ Hp, const bf16_t* __restrict__ Bt,
    const float* __restrict__ rB, const int* __restrict__ rowid,
    const float* __restrict__ s1p, bf16_t* __restrict__ mid) {
  __shared__ bf16_t As[128 * 64];
  __shared__ bf16_t Bs[128 * 64];

  const int tid = threadIdx.x, lane = tid & 63, w = tid >> 6;
  const int wr = w >> 1, wc = w & 1, quad = lane >> 4, l16 = lane & 15;
  const int m0 = blockIdx.x * 128, n0 = blockIdx.y * 128;
  const char* Ab = (const char*)Hp;
  const char* Bb = (const char*)Bt;

  size_t aoff[4], boff[4];
  int cb[4];
#pragma unroll
  for (int c = 0; c < 4; ++c) {
    cb[c] = (w * 4 + c) * 1024;
    const int o = cb[c] + lane * 16;
    const int row = o >> 7;
    const int kb = (o & 127) ^ ((row & 7) << 4);
    aoff[c] = (size_t)(m0 + row) * (HID * 2) + kb;
    boff[c] = (size_t)(n0 + row) * (HID * 2) + kb;
  }
  const int sw = (l16 & 7) << 3;

  const f32x4 fz = {0.f, 0.f, 0.f, 0.f};
  f32x4 acc[4][4];
#pragma unroll
  for (int i = 0; i < 4; ++i)
#pragma unroll
    for (int j = 0; j < 4; ++j) acc[i][j] = fz;

  for (int kt = 0; kt < HID / 64; ++kt) {
    __syncthreads();
#pragma unroll
    for (int c = 0; c < 4; ++c) {
      ASYNC16(Ab + aoff[c] + (size_t)kt * 128, (char*)As + cb[c]);
      ASYNC16(Bb + boff[c] + (size_t)kt * 128, (char*)Bs + cb[c]);
    }
    __syncthreads();

#pragma unroll
    for (int ks = 0; ks < 2; ++ks) {
      const int co = (ks * 32 + quad * 8) ^ sw;
      bf16x8 af[4], bfr[4];
#pragma unroll
      for (int i = 0; i < 4; ++i)
        af[i] = *(const bf16x8*)&As[(wr * 64 + i * 16 + l16) * 64 + co];
#pragma unroll
      for (int j = 0; j < 4; ++j)
        bfr[j] = *(const bf16x8*)&Bs[(wc * 64 + j * 16 + l16) * 64 + co];
#pragma unroll
      for (int i = 0; i < 4; ++i)
#pragma unroll
        for (int j = 0; j < 4; ++j)
          acc[i][j] = __builtin_amdgcn_mfma_f32_16x16x32_bf16(
              af[i], bfr[j], acc[i][j], 0, 0, 0);
    }
  }

  float rbb[4];
  int colj[4];
#pragma unroll
  for (int j = 0; j < 4; ++j) {
    colj[j] = n0 + wc * 64 + j * 16 + l16;
    rbb[j] = rB[colj[j]];
  }
#pragma unroll
  for (int i = 0; i < 4; ++i) {
#pragma unroll
    for (int r = 0; r < 4; ++r) {
      const int p = m0 + wr * 64 + i * 16 + quad * 4 + r;
      const int grow = rowid[p];
      const float s1 = s1p[p];
#pragma unroll
      for (int j = 0; j < 4; ++j) {
        const size_t ix = (size_t)grow * HID + colj[j];
        const float v =
            CLAMP1E4(s1 * (acc[i][j][r] + rbb[j]) + (float)mid[ix]);
        mid[ix] = (bf16_t)v;
      }
    }
  }
}

// ---------------------------------------------------------------------------
// dec: out = mid @ dec_W + dec_b; BK=64 + swizzled LDS; output dtype per flag.
// ---------------------------------------------------------------------------
__global__ __launch_bounds__(256) void dec_gemm(
    const bf16_t* __restrict__ A, const bf16_t* __restrict__ Bt,
    const float* __restrict__ bias, void* __restrict__ C,
    const int* __restrict__ flagp) {
  __shared__ bf16_t As[128 * 64];
  __shared__ bf16_t Bs[128 * 64];

  const int fl = *flagp;
  const int tid = threadIdx.x, lane = tid & 63, w = tid >> 6;
  const int wr = w >> 1, wc = w & 1, quad = lane >> 4, l16 = lane & 15;
  const int m0 = blockIdx.x * 128, n0 = blockIdx.y * 128;
  const char* Ab = (const char*)A;
  const char* Bb = (const char*)Bt;

  size_t aoff[4], boff[4];
  int cb[4];
#pragma unroll
  for (int c = 0; c < 4; ++c) {
    cb[c] = (w * 4 + c) * 1024;
    const int o = cb[c] + lane * 16;
    const int row = o >> 7;
    const int kb = (o & 127) ^ ((row & 7) << 4);
    aoff[c] = (size_t)(m0 + row) * (HID * 2) + kb;
    boff[c] = (size_t)(n0 + row) * (HID * 2) + kb;
  }
  const int sw = (l16 & 7) << 3;

  const f32x4 fz = {0.f, 0.f, 0.f, 0.f};
  f32x4 acc[4][4];
#pragma unroll
  for (int i = 0; i < 4; ++i)
#pragma unroll
    for (int j = 0; j < 4; ++j) acc[i][j] = fz;

  for (int kt = 0; kt < HID / 64; ++kt) {
    __syncthreads();
#pragma unroll
    for (int c = 0; c < 4; ++c) {
      ASYNC16(Ab + aoff[c] + (size_t)kt * 128, (char*)As + cb[c]);
      ASYNC16(Bb + boff[c] + (size_t)kt * 128, (char*)Bs + cb[c]);
    }
    __syncthreads();

#pragma unroll
    for (int ks = 0; ks < 2; ++ks) {
      const int co = (ks * 32 + quad * 8) ^ sw;
      bf16x8 af[4], bfr[4];
#pragma unroll
      for (int i = 0; i < 4; ++i)
        af[i] = *(const bf16x8*)&As[(wr * 64 + i * 16 + l16) * 64 + co];
#pragma unroll
      for (int j = 0; j < 4; ++j)
        bfr[j] = *(const bf16x8*)&Bs[(wc * 64 + j * 16 + l16) * 64 + co];
#pragma unroll
      for (int i = 0; i < 4; ++i)
#pragma unroll
        for (int j = 0; j < 4; ++j)
          acc[i][j] = __builtin_amdgcn_mfma_f32_16x16x32_bf16(
              af[i], bfr[j], acc[i][j], 0, 0, 0);
    }
  }

  float bb[4];
  int colj[4];
#pragma unroll
  for (int j = 0; j < 4; ++j) {
    colj[j] = n0 + wc * 64 + j * 16 + l16;
    bb[j] = bias[colj[j]];
  }
#pragma unroll
  for (int i = 0; i < 4; ++i) {
#pragma unroll
    for (int r = 0; r < 4; ++r) {
      const int row = m0 + wr * 64 + i * 16 + quad * 4 + r;
#pragma unroll
      for (int j = 0; j < 4; ++j) {
        const float v = CLAMP1E4(acc[i][j][r] + bb[j]);
        const size_t ix = (size_t)row * IN_DIM + colj[j];
        if (fl)
          ((float*)C)[ix] = v;
        else
          ((bf16_t*)C)[ix] = (bf16_t)v;
      }
    }
  }
}

// ---------------------------------------------------------------------------
// small-path fallbacks (BK=32, R1 behavior; used only if ws can't hold wTall)
// ---------------------------------------------------------------------------
__global__ __launch_bounds__(256) void bucket_rows(
    const int* __restrict__ eidx, int* __restrict__ curs,
    int* __restrict__ perm) {
  const int r = blockIdx.x * 256 + threadIdx.x;
  const int e = eidx[r];
  const int pos = atomicAdd(&curs[e], 1);
  perm[(size_t)e * N_TOK + pos] = r;
}

__global__ __launch_bounds__(256) void expert_gemm(
    const bf16_t* __restrict__ H, const bf16_t* __restrict__ wTe,
    const float* __restrict__ eBe, const int* __restrict__ permE,
    const int* __restrict__ cnt, int e, const float* __restrict__ s0g,
    bf16_t* __restrict__ mid) {
  __shared__ bf16_t As[128 * 32];
  __shared__ bf16_t Bs[128 * 32];
  __shared__ int rows_s[128];
  __shared__ float s0_s[128];

  const int cnte = cnt[e];
  const int lt = blockIdx.x;
  if (lt * 128 >= cnte) return;
  int nrows = cnte - lt * 128;
  if (nrows > 128) nrows = 128;

  const int tid = threadIdx.x, lane = tid & 63, w = tid >> 6;
  const int wr = w >> 1, wc = w & 1, quad = lane >> 4, l16 = lane & 15;

  if (tid < 128) {
    int grow = -1;
    float a0 = 0.f;
    if (tid < nrows) {
      grow = permE[lt * 128 + tid];
      a0 = s0g[grow];
    }
    rows_s[tid] = grow;
    s0_s[tid] = a0;
  }
  __syncthreads();

  const int n0 = blockIdx.y * 128;
  const char* Hb = (const char*)H;
  const char* Wb = (const char*)wTe;

  size_t aoff[2], boff[2];
  int cb[2];
#pragma unroll
  for (int c = 0; c < 2; ++c) {
    cb[c] = (w * 2 + c) * 1024;
    const int o = cb[c] + lane * 16;
    const int row = o >> 6, kb = o & 63;
    int gr = rows_s[row];
    if (gr < 0) gr = 0;
    aoff[c] = (size_t)gr * (HID * 2) + kb;
    boff[c] = (size_t)(n0 + row) * (HID * 2) + kb;
  }

  const f32x4 fz = {0.f, 0.f, 0.f, 0.f};
  f32x4 acc[4][4];
#pragma unroll
  for (int i = 0; i < 4; ++i)
#pragma unroll
    for (int j = 0; j < 4; ++j) acc[i][j] = fz;

  for (int kt = 0; kt < HID / 32; ++kt) {
    __syncthreads();
#pragma unroll
    for (int c = 0; c < 2; ++c) {
      ASYNC16(Hb + aoff[c] + (size_t)kt * 64, (char*)As + cb[c]);
      ASYNC16(Wb + boff[c] + (size_t)kt * 64, (char*)Bs + cb[c]);
    }
    __syncthreads();

    bf16x8 af[4], bfr[4];
#pragma unroll
    for (int i = 0; i < 4; ++i)
      af[i] = *(const bf16x8*)&As[(wr * 64 + i * 16 + l16) * 32 + quad * 8];
#pragma unroll
    for (int j = 0; j < 4; ++j)
      bfr[j] = *(const bf16x8*)&Bs[(wc * 64 + j * 16 + l16) * 32 + quad * 8];
#pragma unroll
    for (int i = 0; i < 4; ++i)
#pragma unroll
      for (int j = 0; j < 4; ++j)
        acc[i][j] = __builtin_amdgcn_mfma_f32_16x16x32_bf16(af[i], bfr[j],
                                                            acc[i][j], 0, 0, 0);
  }

  float beb[4];
  int colj[4];
#pragma unroll
  for (int j = 0; j < 4; ++j) {
    colj[j] = n0 + wc * 64 + j * 16 + l16;
    beb[j] = eBe[colj[j]];
  }
#pragma unroll
  for (int i = 0; i < 4; ++i) {
#pragma unroll
    for (int r = 0; r < 4; ++r) {
      const int lr = wr * 64 + i * 16 + quad * 4 + r;
      const int grow = rows_s[lr];
      if (grow < 0) continue;
      const float s0 = s0_s[lr];
#pragma unroll
      for (int j = 0; j < 4; ++j) {
        const float v = CLAMP1E4(s0 * (acc[i][j][r] + beb[j]));
        mid[(size_t)grow * HID + colj[j]] = (bf16_t)v;
      }
    }
  }
}

__global__ __launch_bounds__(256) void res_gemm(
    const bf16_t* __restrict__ H, const bf16_t* __restrict__ Bt,
    const float* __restrict__ rB, const float* __restrict__ s1g,
    bf16_t* __restrict__ mid) {
  __shared__ bf16_t As[128 * 32];
  __shared__ bf16_t Bs[128 * 32];

  const int tid = threadIdx.x, lane = tid & 63, w = tid >> 6;
  const int wr = w >> 1, wc = w & 1, quad = lane >> 4, l16 = lane & 15;
  const int m0 = blockIdx.x * 128, n0 = blockIdx.y * 128;
  const char* Ab = (const char*)H;
  const char* Bb = (const char*)Bt;

  size_t aoff[2], boff[2];
  int cb[2];
#pragma unroll
  for (int c = 0; c < 2; ++c) {
    cb[c] = (w * 2 + c) * 1024;
    const int o = cb[c] + lane * 16;
    const int row = o >> 6, kb = o & 63;
    aoff[c] = (size_t)(m0 + row) * (HID * 2) + kb;
    boff[c] = (size_t)(n0 + row) * (HID * 2) + kb;
  }

  const f32x4 fz = {0.f, 0.f, 0.f, 0.f};
  f32x4 acc[4][4];
#pragma unroll
  for (int i = 0; i < 4; ++i)
#pragma unroll
    for (int j = 0; j < 4; ++j) acc[i][j] = fz;

  for (int kt = 0; kt < HID / 32; ++kt) {
    __syncthreads();
#pragma unroll
    for (int c = 0; c < 2; ++c) {
      ASYNC16(Ab + aoff[c] + (size_t)kt * 64, (char*)As + cb[c]);
      ASYNC16(Bb + boff[c] + (size_t)kt * 64, (char*)Bs + cb[c]);
    }
    __syncthreads();

    bf16x8 af[4], bfr[4];
#pragma unroll
    for (int i = 0; i < 4; ++i)
      af[i] = *(const bf16x8*)&As[(wr * 64 + i * 16 + l16) * 32 + quad * 8];
#pragma unroll
    for (int j = 0; j < 4; ++j)
      bfr[j] = *(const bf16x8*)&Bs[(wc * 64 + j * 16 + l16) * 32 + quad * 8];
#pragma unroll
    for (int i = 0; i < 4; ++i)
#pragma unroll
      for (int j = 0; j < 4; ++j)
        acc[i][j] = __builtin_amdgcn_mfma_f32_16x16x32_bf16(af[i], bfr[j],
                                                            acc[i][j], 0, 0, 0);
  }

  float rbb[4];
  int colj[4];
#pragma unroll
  for (int j = 0; j < 4; ++j) {
    colj[j] = n0 + wc * 64 + j * 16 + l16;
    rbb[j] = rB[colj[j]];
  }
#pragma unroll
  for (int i = 0; i < 4; ++i) {
#pragma unroll
    for (int r = 0; r < 4; ++r) {
      const int row = m0 + wr * 64 + i * 16 + quad * 4 + r;
      const float s1 = s1g[row];
#pragma unroll
      for (int j = 0; j < 4; ++j) {
        const size_t ix = (size_t)row * HID + colj[j];
        const float v =
            CLAMP1E4(s1 * (acc[i][j][r] + rbb[j]) + (float)mid[ix]);
        mid[ix] = (bf16_t)v;
      }
    }
  }
}

// ---------------------------------------------------------------------------
extern "C" void kernel_launch(void* const* d_in, const int* in_sizes, int n_in,
                              void* d_out, int out_size, void* d_ws,
                              size_t ws_size, hipStream_t stream) {
  (void)in_sizes; (void)n_in;

  const void* x     = d_in[0];
  const void* encW  = d_in[1];
  const void* encB  = d_in[2];
  const void* gateW = d_in[3];
  const void* expW  = d_in[4];
  const void* expB  = d_in[5];
  const void* resW  = d_in[6];
  const void* resB  = d_in[7];
  const void* coefW = d_in[8];
  const void* coefB = d_in[9];
  const void* decW  = d_in[10];
  const void* decB  = d_in[11];

  // --- workspace layout: ~142MB base, +80MB wTall if available ---
  char* ws = (char*)d_ws;
  size_t o = 0;
  int*    flag  = (int*)(ws + o);    o += 256;
  int*    cnt   = (int*)(ws + o);    o += 256;   // cnt[0..7]; acnt@[8]; curs@[16..23]
  int*    acnt  = cnt + 8;
  int*    curs  = cnt + 16;
  float*  s0g   = (float*)(ws + o);  o += (size_t)N_TOK * 4;
  float*  s1g   = (float*)(ws + o);  o += (size_t)N_TOK * 4;
  float*  c0g   = (float*)(ws + o);  o += (size_t)N_TOK * 4;
  int*    eidx  = (int*)(ws + o);    o += (size_t)N_TOK * 4;
  int*    ambig = (int*)(ws + o);    o += (size_t)N_TOK * 4;
  int*    permfl= (int*)(ws + o);    o += (size_t)N_TOK * 4;
  int*    rowid = (int*)(ws + o);    o += (size_t)N_TOK * 4;
  float*  s0p   = (float*)(ws + o);  o += (size_t)N_TOK * 4;
  float*  s1p   = (float*)(ws + o);  o += (size_t)N_TOK * 4;
  int*    perm  = (int*)(ws + o);    o += (size_t)NEXP * N_TOK * 4;  // small path
  float*  encBf = (float*)(ws + o);  o += HID * 4;
  float*  expBf = (float*)(ws + o);  o += (size_t)NEXP * HID * 4;
  float*  resBf = (float*)(ws + o);  o += HID * 4;
  float*  decBf = (float*)(ws + o);  o += IN_DIM * 4;
  float*  coefBf= (float*)(ws + o);  o += 256;
  bf16_t* gWb   = (bf16_t*)(ws + o); o += (size_t)HID * 8 * 2;
  bf16_t* cWb   = (bf16_t*)(ws + o); o += (size_t)HID * 2 * 2;
  o = (o + 255) & ~(size_t)255;
  bf16_t* bufA  = (bf16_t*)(ws + o); o += (size_t)N_TOK * HID * 2;   // 64 MB
  bf16_t* bufB  = (bf16_t*)(ws + o); o += (size_t)N_TOK * HID * 2;   // 64 MB
  bf16_t* wT    = (bf16_t*)(ws + o); o += (size_t)HID * HID * 2;     // 8 MB
  const size_t needed_small = o;
  const size_t S = (size_t)HID * HID;  // elements per wTall slot
  bf16_t* wTall = (bf16_t*)(ws + o);   // slots 0..7 experts, 8 res, 9 dec
  const size_t needed_big = o + 10 * S * 2;                          // +80 MB

  // pglg (f64 rescue partials, 1024 rows x 8 slices x 8 experts = 512KB)
  // aliases perm: perm is only written by place/bucket_rows AFTER rescue.
  double* pglg = (double*)perm;

  // buffer roles:
  //  big:   xbf=bufB -> enc writes H=bufA -> gather writes Hperm=bufB
  //         -> expert writes mid=bufA -> res RMWs mid -> dec reads bufA
  //  small: xbf=bufB(=mid alias) -> enc writes H=bufA -> experts write
  //         mid=bufB -> dec reads bufB (R1 behavior)
  bf16_t* hbuf  = bufA;
  bf16_t* xbf   = bufB;

  if (ws_size < needed_small) {
    const float v = (float)(ws_size >> 20);  // report budget in MB
    fill_bf16<<<dim3((out_size + 255) / 256), 256, 0, stream>>>(
        (bf16_t*)d_out, v, out_size);
    return;
  }
  const bool big = ws_size >= needed_big;

  detect_dtype<<<1, 256, 0, stream>>>((const ushort_t*)x, flag);
  hipMemsetAsync(cnt, 0, 256, stream);

  // --- normalize inputs ---
  cvt_to_bf16_x4<<<dim3(N_TOK * IN_DIM / 4 / 256), 256, 0, stream>>>(
      x, xbf, N_TOK * IN_DIM / 4, flag);
  cvt_small<<<dim3(64, 7), 256, 0, stream>>>(encB, expB, resB, decB, coefB,
                                             gateW, coefW, encBf, expBf, resBf,
                                             decBf, coefBf, gWb, cWb, flag);

  const dim3 tb(32, 8, 1);

  // --- weight prep ---
  transpose_cvt<<<dim3(HID / 32, IN_DIM / 32, 1), tb, 0, stream>>>(
      encW, (ushort_t*)wT, IN_DIM, HID, 0, flag, 0, 0);
  if (big) {
    transpose_cvt<<<dim3(HID / 32, HID / 32, NEXP), tb, 0, stream>>>(
        expW, (ushort_t*)wTall, HID, HID, 0, flag, S, S);
    transpose_cvt<<<dim3(HID / 32, HID / 32, 1), tb, 0, stream>>>(
        resW, (ushort_t*)(wTall + 8 * S), HID, HID, 0, flag, 0, 0);
    transpose_cvt<<<dim3(IN_DIM / 32, HID / 32, 1), tb, 0, stream>>>(
        decW, (ushort_t*)(wTall + 9 * S), HID, IN_DIM, 0, flag, 0, 0);
  }

  // --- enc + gating ---
  enc_gemm<<<dim3(N_TOK / 128, HID / 128), 256, 0, stream>>>(xbf, wT, encBf,
                                                             hbuf);
  gate_from_h<<<dim3(N_TOK / 16), 256, 0, stream>>>(
      hbuf, gWb, cWb, coefBf, s0g, s1g, c0g, eidx, ambig, acnt, cnt);
  // tiled f64 rescue (8 rows/block share W-slice reads), fixed-order combine
  rescue_tile<<<dim3(128, 8), 256, 0, stream>>>(x, encW, encBf, gateW, flag,
                                                ambig, acnt, pglg);
  rescue_final<<<dim3(1024), 64, 0, stream>>>(ambig, acnt, c0g, pglg, s0g,
                                              eidx, cnt);
  // overflow guard for acnt > 1024 (whole-row legacy path; normally no-op)
  rescue_rows<<<dim3(N_TOK - 1024), 256, 0, stream>>>(
      x, encW, encBf, gateW, flag, ambig, acnt, c0g, s0g, eidx, cnt, 1024);

  if (big) {
    bf16_t* Hperm = bufB;  // xbf dead after enc_gemm
    bf16_t* mid   = bufA;  // H dead after gather
    place_rows<<<dim3(N_TOK / 256), 256, 0, stream>>>(eidx, cnt, curs, permfl);
    gather_rows<<<dim3(N_TOK / 4), 256, 0, stream>>>(hbuf, permfl, s0g, s1g,
                                                     Hperm, rowid, s0p, s1p);
    expert_gemm_t<<<dim3(136, HID / 128), 256, 0, stream>>>(
        Hperm, wTall, S, expBf, cnt, rowid, s0p, mid);
    res_gemm_p<<<dim3(N_TOK / 128, HID / 128), 256, 0, stream>>>(
        Hperm, wTall + 8 * S, resBf, rowid, s1p, mid);
    dec_gemm<<<dim3(N_TOK / 128, IN_DIM / 128), 256, 0, stream>>>(
        mid, wTall + 9 * S, decBf, d_out, flag);
  } else {
    // --- fallback: serial per-expert path (R1 behavior) ---
    bf16_t* mid = bufB;  // xbf dead after enc_gemm
    bucket_rows<<<dim3(N_TOK / 256), 256, 0, stream>>>(eidx, curs, perm);
    for (int e = 0; e < NEXP; ++e) {
      transpose_cvt<<<dim3(HID / 32, HID / 32, 1), tb, 0, stream>>>(
          expW, (ushort_t*)wT, HID, HID, (size_t)e * HID * HID, flag, 0, 0);
      expert_gemm<<<dim3(N_TOK / 128, HID / 128), 256, 0, stream>>>(
          hbuf, wT, expBf + (size_t)e * HID, perm + (size_t)e * N_TOK, cnt, e,
          s0g, mid);
    }
    transpose_cvt<<<dim3(HID / 32, HID / 32, 1), tb, 0, stream>>>(
        resW, (ushort_t*)wT, HID, HID, 0, flag, 0, 0);
    res_gemm<<<dim3(N_TOK / 128, HID / 128), 256, 0, stream>>>(hbuf, wT, resBf,
                                                               s1g, mid);
    transpose_cvt<<<dim3(IN_DIM / 32, HID / 32, 1), tb, 0, stream>>>(
        decW, (ushort_t*)wT, HID, IN_DIM, 0, flag, 0, 0);
    dec_gemm<<<dim3(N_TOK / 128, IN_DIM / 128), 256, 0, stream>>>(
        mid, wT, decBf, d_out, flag);
  }
}

// Round 8
// 1346.122 us; speedup vs baseline: 1.3044x; 1.3044x over previous
//
#include <hip/hip_runtime.h>

// ---------------------------------------------------------------------------
// MoE Autoencoder, MI355X (gfx950). DTYPE-ADAPTIVE (f32 or bf16 inputs).
// R8 changes vs R7 (1755us):
//  - rescue_tile REGRESSED 289->487us: W-reuse cut traffic 8x but active
//    blocks fell to 240 (~1 wave/SIMD, occ 11.6%, VALU 6.7%) -- every W-load
//    latency fully exposed. rescue_tile2 keeps the 8-row W-reuse but splits
//    the block 2-D: 64 cols x 4 k-quarters per 256-thread block, grid
//    (128, 32) -> 960 active blocks, per-thread FMA 8192->2048. Quarters
//    combine via LDS in fixed order; wave-0 does relu+gate-logits +
//    64-lane butterfly; pglg[row][32][8] lives in bufB (dead window).
//  - TAU stays 3e-3 (R7 confirmed acnt ~240 via WRITE_SIZE).
//  - GEMMs unchanged (BK=64 + swizzle).
// ---------------------------------------------------------------------------

#define N_TOK 16384
#define IN_DIM 1024
#define HID 2048
#define NEXP 8
#define TAU 3.0e-3f
#define RROWS 8

typedef __bf16 bf16_t;
typedef __bf16 bf16x8 __attribute__((ext_vector_type(8)));
typedef __bf16 bf16x4v __attribute__((ext_vector_type(4)));
typedef float f32x4 __attribute__((ext_vector_type(4)));
typedef unsigned short ushort_t;

#define CLAMP1E4(v) fmaxf(fminf((v), 1.0e4f), -1.0e4f)

#define ASYNC16(gp, lp)                                                        \
  __builtin_amdgcn_global_load_lds(                                            \
      (const __attribute__((address_space(1))) void*)(gp),                     \
      (__attribute__((address_space(3))) void*)(lp), 16, 0, 0)

static __device__ inline ushort_t b2u(bf16_t v) {
  union { bf16_t b; ushort_t u; } x; x.b = v; return x.u;
}

// ---------------------------------------------------------------------------
__global__ __launch_bounds__(256) void fill_bf16(bf16_t* __restrict__ p,
                                                 float v, int n) {
  const int i = blockIdx.x * 256 + threadIdx.x;
  if (i < n) p[i] = (bf16_t)v;
}

// ---------------------------------------------------------------------------
// flag=1  <=>  raw data is f32 (reading it as bf16 yields wild exponents)
// ---------------------------------------------------------------------------
__global__ __launch_bounds__(256) void detect_dtype(
    const ushort_t* __restrict__ xr, int* __restrict__ flag) {
  __shared__ int s_bad;
  if (threadIdx.x == 0) s_bad = 0;
  __syncthreads();
  int bad = 0;
  for (int i = threadIdx.x; i < 4096; i += 256) {
    const int e = (xr[i] >> 7) & 0xFF;
    if (e >= 0xC0) bad = 1;  // |v| >= 2^65: impossible for real bf16 data
  }
  if (__any(bad) && (threadIdx.x & 63) == 0) atomicOr(&s_bad, 1);
  __syncthreads();
  if (threadIdx.x == 0) *flag = s_bad;
}

// ---------------------------------------------------------------------------
// vectorized x4 conversion for the big x buffer
__global__ __launch_bounds__(256) void cvt_to_bf16_x4(
    const void* __restrict__ src, bf16_t* __restrict__ dst, int n4,
    const int* __restrict__ flagp) {
  const int f = *flagp;
  const int i = blockIdx.x * 256 + threadIdx.x;
  if (i >= n4) return;
  bf16x4v o;
  if (f) {
    const f32x4 v = ((const f32x4*)src)[i];
    o[0] = (bf16_t)v[0]; o[1] = (bf16_t)v[1];
    o[2] = (bf16_t)v[2]; o[3] = (bf16_t)v[3];
  } else {
    o = ((const bf16x4v*)src)[i];
  }
  ((bf16x4v*)dst)[i] = o;
}

// ---------------------------------------------------------------------------
// all small conversions in one launch. blockIdx.y = segment.
// ---------------------------------------------------------------------------
__global__ __launch_bounds__(256) void cvt_small(
    const void* __restrict__ encB, const void* __restrict__ expB,
    const void* __restrict__ resB, const void* __restrict__ decB,
    const void* __restrict__ coefB, const void* __restrict__ gateW,
    const void* __restrict__ coefW, float* __restrict__ encBf,
    float* __restrict__ expBf, float* __restrict__ resBf,
    float* __restrict__ decBf, float* __restrict__ coefBf,
    bf16_t* __restrict__ gWb, bf16_t* __restrict__ cWb,
    const int* __restrict__ flagp) {
  const int f = *flagp;
  const int i = blockIdx.x * 256 + threadIdx.x;
  const int seg = blockIdx.y;
  const void* src;
  int n;
  switch (seg) {
    case 0: src = encB;  n = HID; break;
    case 1: src = expB;  n = NEXP * HID; break;
    case 2: src = resB;  n = HID; break;
    case 3: src = decB;  n = IN_DIM; break;
    case 4: src = coefB; n = 2; break;
    case 5: src = gateW; n = HID * 8; break;
    default: src = coefW; n = HID * 2; break;
  }
  if (i >= n) return;
  const float v = f ? ((const float*)src)[i] : (float)((const bf16_t*)src)[i];
  switch (seg) {
    case 0: encBf[i] = v; break;
    case 1: expBf[i] = v; break;
    case 2: resBf[i] = v; break;
    case 3: decBf[i] = v; break;
    case 4: coefBf[i] = v; break;
    case 5: gWb[i] = (bf16_t)v; break;
    default: cWb[i] = (bf16_t)v; break;
  }
}

// ---------------------------------------------------------------------------
// transpose + convert: src[R][C] (f32 or bf16 per flag) -> dst[C][R] bf16.
// ---------------------------------------------------------------------------
__global__ __launch_bounds__(256) void transpose_cvt(
    const void* __restrict__ src0, ushort_t* __restrict__ dst, int R, int C,
    size_t elem_off, const int* __restrict__ flagp, size_t src_zstride,
    size_t dst_zstride) {
  __shared__ ushort_t t[32][33];
  const int f = *flagp;
  const size_t eoff = elem_off + (size_t)blockIdx.z * src_zstride;
  dst += (size_t)blockIdx.z * dst_zstride;
  const int c0 = blockIdx.x * 32, r0 = blockIdx.y * 32;
  const int tx = threadIdx.x, ty = threadIdx.y;
  if (f) {
    const float* s = (const float*)src0 + eoff;
#pragma unroll
    for (int i = 0; i < 4; ++i)
      t[ty + i * 8][tx] =
          b2u((bf16_t)s[(size_t)(r0 + ty + i * 8) * C + c0 + tx]);
  } else {
    const ushort_t* s = (const ushort_t*)src0 + eoff;
#pragma unroll
    for (int i = 0; i < 4; ++i)
      t[ty + i * 8][tx] = s[(size_t)(r0 + ty + i * 8) * C + c0 + tx];
  }
  __syncthreads();
#pragma unroll
  for (int i = 0; i < 4; ++i)
    dst[(size_t)(c0 + ty + i * 8) * R + r0 + tx] = t[tx][ty + i * 8];
}

// ---------------------------------------------------------------------------
// Shared BK=64 GEMM geometry (128x128 tile, [128][64] bf16 LDS per matrix,
// swizzled: achieved by permuting the per-lane GLOBAL source and XOR-ing the
// ds_read column. 2 K-sub-steps of 16 MFMA each.
// ---------------------------------------------------------------------------

// enc: h = relu(x @ enc_W + b) (bf16). K = IN_DIM (16 K-steps).
__global__ __launch_bounds__(256) void enc_gemm(
    const bf16_t* __restrict__ A, const bf16_t* __restrict__ Bt,
    const float* __restrict__ bias, bf16_t* __restrict__ H) {
  __shared__ bf16_t As[128 * 64];
  __shared__ bf16_t Bs[128 * 64];

  const int tid = threadIdx.x, lane = tid & 63, w = tid >> 6;
  const int wr = w >> 1, wc = w & 1, quad = lane >> 4, l16 = lane & 15;
  const int m0 = blockIdx.x * 128, n0 = blockIdx.y * 128;
  const char* Ab = (const char*)A;
  const char* Bb = (const char*)Bt;
  const size_t lda = (size_t)IN_DIM * 2;

  const f32x4 fz = {0.f, 0.f, 0.f, 0.f};
  f32x4 acc[4][4];
#pragma unroll
  for (int i = 0; i < 4; ++i)
#pragma unroll
    for (int j = 0; j < 4; ++j) acc[i][j] = fz;

  size_t aoff[4], boff[4];
  int cb[4];
#pragma unroll
  for (int c = 0; c < 4; ++c) {
    cb[c] = (w * 4 + c) * 1024;
    const int o = cb[c] + lane * 16;
    const int row = o >> 7;
    const int kb = (o & 127) ^ ((row & 7) << 4);  // pre-swizzled source
    aoff[c] = (size_t)(m0 + row) * lda + kb;
    boff[c] = (size_t)(n0 + row) * lda + kb;
  }
  const int sw = (l16 & 7) << 3;  // element-space read swizzle

  for (int kt = 0; kt < IN_DIM / 64; ++kt) {
    __syncthreads();
#pragma unroll
    for (int c = 0; c < 4; ++c) {
      ASYNC16(Ab + aoff[c] + (size_t)kt * 128, (char*)As + cb[c]);
      ASYNC16(Bb + boff[c] + (size_t)kt * 128, (char*)Bs + cb[c]);
    }
    __syncthreads();

#pragma unroll
    for (int ks = 0; ks < 2; ++ks) {
      const int co = (ks * 32 + quad * 8) ^ sw;
      bf16x8 af[4], bfr[4];
#pragma unroll
      for (int i = 0; i < 4; ++i)
        af[i] = *(const bf16x8*)&As[(wr * 64 + i * 16 + l16) * 64 + co];
#pragma unroll
      for (int j = 0; j < 4; ++j)
        bfr[j] = *(const bf16x8*)&Bs[(wc * 64 + j * 16 + l16) * 64 + co];
#pragma unroll
      for (int i = 0; i < 4; ++i)
#pragma unroll
        for (int j = 0; j < 4; ++j)
          acc[i][j] = __builtin_amdgcn_mfma_f32_16x16x32_bf16(
              af[i], bfr[j], acc[i][j], 0, 0, 0);
    }
  }

  float bj[4];
  int colj[4];
#pragma unroll
  for (int j = 0; j < 4; ++j) {
    colj[j] = n0 + wc * 64 + j * 16 + l16;
    bj[j] = bias[colj[j]];
  }

#pragma unroll
  for (int i = 0; i < 4; ++i) {
#pragma unroll
    for (int r = 0; r < 4; ++r) {
      const int row = m0 + wr * 64 + i * 16 + quad * 4 + r;
#pragma unroll
      for (int j = 0; j < 4; ++j) {
        const float v = fminf(fmaxf(acc[i][j][r] + bj[j], 0.f), 1.0e4f);
        H[(size_t)row * HID + colj[j]] = (bf16_t)v;
      }
    }
  }
}

// ---------------------------------------------------------------------------
// gate_from_h: one wave per 4 rows; gate/coef logits + softmax/argmax;
// counts per expert; ambiguous rows -> rescue list.
// ---------------------------------------------------------------------------
__global__ __launch_bounds__(256) void gate_from_h(
    const bf16_t* __restrict__ H, const bf16_t* __restrict__ gW,
    const bf16_t* __restrict__ cW, const float* __restrict__ coefBf,
    float* __restrict__ s0g, float* __restrict__ s1g, float* __restrict__ c0g,
    int* __restrict__ eidx, int* __restrict__ ambig, int* __restrict__ acnt,
    int* __restrict__ cnt) {
  const int tid = threadIdx.x, lane = tid & 63, w = tid >> 6;
  const int r0 = blockIdx.x * 16 + w * 4;  // 4 waves * 4 rows per block

  float acc[4][10];
#pragma unroll
  for (int g = 0; g < 4; ++g)
#pragma unroll
    for (int o = 0; o < 10; ++o) acc[g][o] = 0.f;

#pragma unroll
  for (int it = 0; it < HID / 512; ++it) {  // 4 iterations
    const int h0 = it * 512 + lane * 8;
    bf16x8 hv[4];
#pragma unroll
    for (int g = 0; g < 4; ++g)
      hv[g] = *(const bf16x8*)(H + (size_t)(r0 + g) * HID + h0);
    const bf16_t* gp = gW + (size_t)h0 * 8;
    const bf16_t* cp = cW + (size_t)h0 * 2;
    bf16x8 cc0 = *(const bf16x8*)(cp);
    bf16x8 cc1 = *(const bf16x8*)(cp + 8);
#pragma unroll
    for (int k = 0; k < 8; ++k) {
      const bf16x8 gk = *(const bf16x8*)(gp + k * 8);
      const float ck0 = (k < 4) ? (float)cc0[(k & 3) * 2]
                                : (float)cc1[(k & 3) * 2];
      const float ck1 = (k < 4) ? (float)cc0[(k & 3) * 2 + 1]
                                : (float)cc1[(k & 3) * 2 + 1];
#pragma unroll
      for (int g = 0; g < 4; ++g) {
        const float v = (float)hv[g][k];
#pragma unroll
        for (int o = 0; o < 8; ++o) acc[g][o] += v * (float)gk[o];
        acc[g][8] += v * ck0;
        acc[g][9] += v * ck1;
      }
    }
  }

#pragma unroll
  for (int m = 1; m < 64; m <<= 1)
#pragma unroll
    for (int g = 0; g < 4; ++g)
#pragma unroll
      for (int o = 0; o < 10; ++o) acc[g][o] += __shfl_xor(acc[g][o], m);

  if (lane == 0) {
#pragma unroll
    for (int g = 0; g < 4; ++g) {
      const int r = r0 + g;
      float lv[8];
#pragma unroll
      for (int e = 0; e < 8; ++e) lv[e] = acc[g][e];
      float mx = lv[0];
      int idx = 0;
#pragma unroll
      for (int e = 1; e < 8; ++e)
        if (lv[e] > mx) { mx = lv[e]; idx = e; }
      float s2 = -1.0e30f;
#pragma unroll
      for (int e = 0; e < 8; ++e)
        if (e != idx) s2 = fmaxf(s2, lv[e]);
      float s = 0.f;
#pragma unroll
      for (int e = 0; e < 8; ++e) s += expf(lv[e] - mx);
      const float gate = 1.f / s;
      const float c0 = acc[g][8] + coefBf[0], c1 = acc[g][9] + coefBf[1];
      const float cm = fmaxf(c0, c1);
      const float e0 = expf(c0 - cm), e1 = expf(c1 - cm);
      const float inv = 1.f / (e0 + e1);
      const float p0 = e0 * inv;
      c0g[r] = p0;
      s1g[r] = e1 * inv;
      s0g[r] = gate * p0;
      eidx[r] = idx;
      atomicAdd(&cnt[idx], 1);
      if (mx - s2 < TAU) {
        const int p = atomicAdd(acnt, 1);
        ambig[p] = r;
      }
    }
  }
}

// ---------------------------------------------------------------------------
// rescue_tile2: grid (128, 32). Block (t, slice) = 8 amb rows x 64 cols.
// 256 threads = 64 cols (c) x 4 k-quarters (q): thread (c,q) accumulates the
// f64 h-partial of its column over k in [q*256,(q+1)*256) for all 8 rows
// (x rows staged in LDS, W-slice read once per block -> keeps R7's W-reuse).
// Quarters combine via LDS in FIXED order; wave-0 applies bias+relu, forms
// gate logits, 64-lane butterfly -> pglg[row][32 slices][8]. Deterministic.
// 960 active blocks (vs R7's 240: 1 wave/SIMD, fully latency-exposed).
// ---------------------------------------------------------------------------
__global__ __launch_bounds__(256) void rescue_tile2(
    const void* __restrict__ xraw, const void* __restrict__ encWraw,
    const float* __restrict__ encBf, const void* __restrict__ gateWraw,
    const int* __restrict__ flagp, const int* __restrict__ ambig,
    const int* __restrict__ acnt, double* __restrict__ pglg) {
  const int an0 = *acnt;
  const int an = an0 < 1024 ? an0 : 1024;  // tiled path covers first 1024
  const int i0 = blockIdx.x * RROWS;
  if (i0 >= an) return;
  int nr = an - i0;
  if (nr > RROWS) nr = RROWS;
  const int slice = blockIdx.y;
  const int f = *flagp;
  const int tid = threadIdx.x;
  const int c = tid & 63, q = tid >> 6;
  const int j = slice * 64 + c;  // this thread's h-column
  const int kb = q * 256;       // this thread's k-quarter

  __shared__ int rows_sh[RROWS];
  __shared__ float xs[RROWS][IN_DIM];   // 32 KB
  __shared__ double hp[4][RROWS][64];   // 16 KB: q, r, c

  if (tid < RROWS) rows_sh[tid] = ambig[i0 + (tid < nr ? tid : 0)];
  __syncthreads();

  for (int r = 0; r < RROWS; ++r) {
    const int row = rows_sh[r];
    if (f) {
      const float* xp = (const float*)xraw + (size_t)row * IN_DIM;
      for (int k = tid; k < IN_DIM; k += 256) xs[r][k] = xp[k];
    } else {
      const bf16_t* xp = (const bf16_t*)xraw + (size_t)row * IN_DIM;
      for (int k = tid; k < IN_DIM; k += 256) xs[r][k] = (float)xp[k];
    }
  }
  __syncthreads();

  double hacc[RROWS];
#pragma unroll
  for (int r = 0; r < RROWS; ++r) hacc[r] = 0.0;

  if (f) {
    const float* W = (const float*)encWraw + j;
    for (int k0 = 0; k0 < 256; k0 += 8) {
      double wd[8];
#pragma unroll
      for (int kk = 0; kk < 8; ++kk)
        wd[kk] = (double)W[(size_t)(kb + k0 + kk) * HID];
#pragma unroll
      for (int r = 0; r < RROWS; ++r) {
        const f32x4 xa = *(const f32x4*)&xs[r][kb + k0];
        const f32x4 xb2 = *(const f32x4*)&xs[r][kb + k0 + 4];
        double a = hacc[r];
        a += (double)xa[0] * wd[0];
        a += (double)xa[1] * wd[1];
        a += (double)xa[2] * wd[2];
        a += (double)xa[3] * wd[3];
        a += (double)xb2[0] * wd[4];
        a += (double)xb2[1] * wd[5];
        a += (double)xb2[2] * wd[6];
        a += (double)xb2[3] * wd[7];
        hacc[r] = a;
      }
    }
  } else {
    const bf16_t* W = (const bf16_t*)encWraw + j;
    for (int k0 = 0; k0 < 256; k0 += 8) {
      double wd[8];
#pragma unroll
      for (int kk = 0; kk < 8; ++kk)
        wd[kk] = (double)(float)W[(size_t)(kb + k0 + kk) * HID];
#pragma unroll
      for (int r = 0; r < RROWS; ++r) {
        const f32x4 xa = *(const f32x4*)&xs[r][kb + k0];
        const f32x4 xb2 = *(const f32x4*)&xs[r][kb + k0 + 4];
        double a = hacc[r];
        a += (double)xa[0] * wd[0];
        a += (double)xa[1] * wd[1];
        a += (double)xa[2] * wd[2];
        a += (double)xa[3] * wd[3];
        a += (double)xb2[0] * wd[4];
        a += (double)xb2[1] * wd[5];
        a += (double)xb2[2] * wd[6];
        a += (double)xb2[3] * wd[7];
        hacc[r] = a;
      }
    }
  }

#pragma unroll
  for (int r = 0; r < RROWS; ++r) hp[q][r][c] = hacc[r];
  __syncthreads();

  if (q == 0) {  // wave 0 exactly (tids 0..63)
    double gv[8];
    if (f) {
      const float* g = (const float*)gateWraw + (size_t)j * 8;
#pragma unroll
      for (int e = 0; e < 8; ++e) gv[e] = (double)g[e];
    } else {
      const bf16_t* g = (const bf16_t*)gateWraw + (size_t)j * 8;
#pragma unroll
      for (int e = 0; e < 8; ++e) gv[e] = (double)(float)g[e];
    }
    const double bj = (double)encBf[j];
    for (int r = 0; r < RROWS; ++r) {
      const double h =
          hp[0][r][c] + hp[1][r][c] + hp[2][r][c] + hp[3][r][c] + bj;
      double lg[8];
#pragma unroll
      for (int e = 0; e < 8; ++e) lg[e] = (h > 0.0) ? h * gv[e] : 0.0;
#pragma unroll
      for (int m = 1; m < 64; m <<= 1)
#pragma unroll
        for (int e = 0; e < 8; ++e) lg[e] += __shfl_xor(lg[e], m);
      if (c == 0 && r < nr) {
#pragma unroll
        for (int e = 0; e < 8; ++e)
          pglg[((size_t)(i0 + r) * 32 + slice) * 8 + e] = lg[e];
      }
    }
  }
}

// ---------------------------------------------------------------------------
// rescue_final: sums the 32 slice-partials per row in FIXED order (f64),
// argmax + softmax, updates s0g/eidx/cnt.
// ---------------------------------------------------------------------------
__global__ __launch_bounds__(64) void rescue_final(
    const int* __restrict__ ambig, const int* __restrict__ acnt,
    const float* __restrict__ c0g, const double* __restrict__ pglg,
    float* __restrict__ s0g, int* __restrict__ eidx, int* __restrict__ cnt) {
  const int i = blockIdx.x;
  if (i >= *acnt || threadIdx.x != 0) return;
  const int r = ambig[i];
  double t[8];
#pragma unroll
  for (int e = 0; e < 8; ++e) t[e] = 0.0;
  for (int s = 0; s < 32; ++s) {
#pragma unroll
    for (int e = 0; e < 8; ++e) t[e] += pglg[((size_t)i * 32 + s) * 8 + e];
  }
  double m = t[0];
  int idx = 0;
#pragma unroll
  for (int e = 1; e < 8; ++e)
    if (t[e] > m) { m = t[e]; idx = e; }
  double s = 0.0;
#pragma unroll
  for (int e = 0; e < 8; ++e) s += exp(t[e] - m);
  s0g[r] = (float)((1.0 / s) * (double)c0g[r]);
  const int old = eidx[r];
  if (idx != old) {
    atomicSub(&cnt[old], 1);
    atomicAdd(&cnt[idx], 1);
    eidx[r] = idx;
  }
}

// ---------------------------------------------------------------------------
// rescue_rows (legacy whole-row, ioff-based): guards the acnt>1024 overflow
// of the tiled path (normally a no-op).
// ---------------------------------------------------------------------------
__global__ __launch_bounds__(256) void rescue_rows(
    const void* __restrict__ xraw, const void* __restrict__ encWraw,
    const float* __restrict__ encBf, const void* __restrict__ gateWraw,
    const int* __restrict__ flagp, const int* __restrict__ ambig,
    const int* __restrict__ acnt, const float* __restrict__ c0g,
    float* __restrict__ s0g, int* __restrict__ eidx, int* __restrict__ cnt,
    int ioff) {
  const int i = blockIdx.x + ioff;
  if (i >= *acnt) return;
  const int r = ambig[i];
  const int f = *flagp;
  const int tid = threadIdx.x;

  __shared__ float xs[IN_DIM];
  if (f) {
    const float* xp = (const float*)xraw + (size_t)r * IN_DIM;
    for (int k = tid; k < IN_DIM; k += 256) xs[k] = xp[k];
  } else {
    const bf16_t* xp = (const bf16_t*)xraw + (size_t)r * IN_DIM;
    for (int k = tid; k < IN_DIM; k += 256) xs[k] = (float)xp[k];
  }
  __syncthreads();

  double hacc[8] = {0, 0, 0, 0, 0, 0, 0, 0};
  if (f) {
    const float* W = (const float*)encWraw;
    for (int k0 = 0; k0 < IN_DIM; k0 += 8) {
      float wv[8][8];
#pragma unroll
      for (int kk = 0; kk < 8; ++kk) {
        const float* Wr = W + (size_t)(k0 + kk) * HID + tid;
#pragma unroll
        for (int jj = 0; jj < 8; ++jj) wv[kk][jj] = Wr[jj * 256];
      }
#pragma unroll
      for (int kk = 0; kk < 8; ++kk) {
        const double xv = (double)xs[k0 + kk];
#pragma unroll
        for (int jj = 0; jj < 8; ++jj) hacc[jj] += xv * (double)wv[kk][jj];
      }
    }
  } else {
    const bf16_t* W = (const bf16_t*)encWraw;
    for (int k0 = 0; k0 < IN_DIM; k0 += 8) {
      float wv[8][8];
#pragma unroll
      for (int kk = 0; kk < 8; ++kk) {
        const bf16_t* Wr = W + (size_t)(k0 + kk) * HID + tid;
#pragma unroll
        for (int jj = 0; jj < 8; ++jj) wv[kk][jj] = (float)Wr[jj * 256];
      }
#pragma unroll
      for (int kk = 0; kk < 8; ++kk) {
        const double xv = (double)xs[k0 + kk];
#pragma unroll
        for (int jj = 0; jj < 8; ++jj) hacc[jj] += xv * (double)wv[kk][jj];
      }
    }
  }

  double lg[8] = {0, 0, 0, 0, 0, 0, 0, 0};
#pragma unroll
  for (int jj = 0; jj < 8; ++jj) {
    const int j = tid + jj * 256;
    double h = hacc[jj] + (double)encBf[j];
    if (h > 0.0) {
      if (f) {
        const float* g = (const float*)gateWraw + (size_t)j * 8;
#pragma unroll
        for (int e = 0; e < 8; ++e) lg[e] += h * (double)g[e];
      } else {
        const bf16_t* g = (const bf16_t*)gateWraw + (size_t)j * 8;
#pragma unroll
        for (int e = 0; e < 8; ++e) lg[e] += h * (double)(float)g[e];
      }
    }
  }
#pragma unroll
  for (int m = 1; m < 64; m <<= 1)
#pragma unroll
    for (int e = 0; e < 8; ++e) lg[e] += __shfl_xor(lg[e], m);

  __shared__ double red[4][8];
  const int w = tid >> 6, lane = tid & 63;
  if (lane == 0)
#pragma unroll
    for (int e = 0; e < 8; ++e) red[w][e] = lg[e];
  __syncthreads();
  if (tid == 0) {
    double t[8];
#pragma unroll
    for (int e = 0; e < 8; ++e)
      t[e] = red[0][e] + red[1][e] + red[2][e] + red[3][e];
    double m = t[0];
    int idx = 0;
#pragma unroll
    for (int e = 1; e < 8; ++e)
      if (t[e] > m) { m = t[e]; idx = e; }
    double s = 0.0;
#pragma unroll
    for (int e = 0; e < 8; ++e) s += exp(t[e] - m);
    s0g[r] = (float)((1.0 / s) * (double)c0g[r]);
    const int old = eidx[r];
    if (idx != old) {
      atomicSub(&cnt[old], 1);
      atomicAdd(&cnt[idx], 1);
      eidx[r] = idx;
    }
  }
}

// ---------------------------------------------------------------------------
__global__ __launch_bounds__(256) void place_rows(
    const int* __restrict__ eidx, const int* __restrict__ cnt,
    int* __restrict__ curs, int* __restrict__ permflat) {
  const int r = blockIdx.x * 256 + threadIdx.x;
  const int e = eidx[r];
  int prefix = 0;
  for (int ee = 0; ee < NEXP; ++ee)
    if (ee < e) prefix += cnt[ee];
  const int pos = atomicAdd(&curs[e], 1);
  permflat[prefix + pos] = r;
}

// ---------------------------------------------------------------------------
__global__ __launch_bounds__(256) void gather_rows(
    const bf16_t* __restrict__ H, const int* __restrict__ permflat,
    const float* __restrict__ s0g, const float* __restrict__ s1g,
    bf16_t* __restrict__ Hp, int* __restrict__ rowid,
    float* __restrict__ s0p, float* __restrict__ s1p) {
  const int w = threadIdx.x >> 6, lane = threadIdx.x & 63;
  const int p = blockIdx.x * 4 + w;
  const int r = permflat[p];
  if (lane == 0) {
    rowid[p] = r;
    s0p[p] = s0g[r];
    s1p[p] = s1g[r];
  }
  const bf16x8* src = (const bf16x8*)(H + (size_t)r * HID);
  bf16x8* dst = (bf16x8*)(Hp + (size_t)p * HID);
#pragma unroll
  for (int i = 0; i < 4; ++i) dst[lane + i * 64] = src[lane + i * 64];
}

// ---------------------------------------------------------------------------
// expert_gemm_t: contiguous-A expert GEMM over Hperm, tile table from cnt[].
// BK=64 + swizzled LDS. mid[rowid] = s0 * (h @ We + be).
// ---------------------------------------------------------------------------
__global__ __launch_bounds__(256) void expert_gemm_t(
    const bf16_t* __restrict__ Hp, const bf16_t* __restrict__ wTall,
    size_t wstride, const float* __restrict__ expBf,
    const int* __restrict__ cnt, const int* __restrict__ rowid,
    const float* __restrict__ s0p, bf16_t* __restrict__ mid) {
  __shared__ bf16_t As[128 * 64];
  __shared__ bf16_t Bs[128 * 64];
  __shared__ int rows_s[128];
  __shared__ float s0_s[128];

  // tile table on the fly: x -> (expert e, tile t)
  const int x = blockIdx.x;
  int e = -1, base = 0, nrows = 0;
  {
    int acc = 0, pre = 0;
    for (int ee = 0; ee < NEXP; ++ee) {
      const int ce = cnt[ee];
      const int nt = (ce + 127) >> 7;
      if (x < acc + nt) {
        const int t = x - acc;
        e = ee;
        base = pre + t * 128;
        nrows = ce - t * 128;
        if (nrows > 128) nrows = 128;
        break;
      }
      acc += nt;
      pre += ce;
    }
  }
  if (e < 0) return;

  const int tid = threadIdx.x, lane = tid & 63, w = tid >> 6;
  const int wr = w >> 1, wc = w & 1, quad = lane >> 4, l16 = lane & 15;

  if (tid < 128) {
    int grow = -1;
    float a0 = 0.f;
    if (tid < nrows) {
      grow = rowid[base + tid];
      a0 = s0p[base + tid];
    }
    rows_s[tid] = grow;
    s0_s[tid] = a0;
  }
  __syncthreads();

  const int n0 = blockIdx.y * 128;
  const char* Hb = (const char*)Hp;
  const char* Wb = (const char*)(wTall + (size_t)e * wstride);

  size_t aoff[4], boff[4];
  int cb[4];
#pragma unroll
  for (int c = 0; c < 4; ++c) {
    cb[c] = (w * 4 + c) * 1024;
    const int o = cb[c] + lane * 16;
    const int row = o >> 7;
    const int kb = (o & 127) ^ ((row & 7) << 4);
    int ar = base + row;
    if (ar > N_TOK - 1) ar = N_TOK - 1;  // tail-tile clamp (masked at write)
    aoff[c] = (size_t)ar * (HID * 2) + kb;
    boff[c] = (size_t)(n0 + row) * (HID * 2) + kb;
  }
  const int sw = (l16 & 7) << 3;

  const f32x4 fz = {0.f, 0.f, 0.f, 0.f};
  f32x4 acc[4][4];
#pragma unroll
  for (int i = 0; i < 4; ++i)
#pragma unroll
    for (int j = 0; j < 4; ++j) acc[i][j] = fz;

  for (int kt = 0; kt < HID / 64; ++kt) {
    __syncthreads();
#pragma unroll
    for (int c = 0; c < 4; ++c) {
      ASYNC16(Hb + aoff[c] + (size_t)kt * 128, (char*)As + cb[c]);
      ASYNC16(Wb + boff[c] + (size_t)kt * 128, (char*)Bs + cb[c]);
    }
    __syncthreads();

#pragma unroll
    for (int ks = 0; ks < 2; ++ks) {
      const int co = (ks * 32 + quad * 8) ^ sw;
      bf16x8 af[4], bfr[4];
#pragma unroll
      for (int i = 0; i < 4; ++i)
        af[i] = *(const bf16x8*)&As[(wr * 64 + i * 16 + l16) * 64 + co];
#pragma unroll
      for (int j = 0; j < 4; ++j)
        bfr[j] = *(const bf16x8*)&Bs[(wc * 64 + j * 16 + l16) * 64 + co];
#pragma unroll
      for (int i = 0; i < 4; ++i)
#pragma unroll
        for (int j = 0; j < 4; ++j)
          acc[i][j] = __builtin_amdgcn_mfma_f32_16x16x32_bf16(
              af[i], bfr[j], acc[i][j], 0, 0, 0);
    }
  }

  const float* eBe = expBf + (size_t)e * HID;
  float beb[4];
  int colj[4];
#pragma unroll
  for (int j = 0; j < 4; ++j) {
    colj[j] = n0 + wc * 64 + j * 16 + l16;
    beb[j] = eBe[colj[j]];
  }
#pragma unroll
  for (int i = 0; i < 4; ++i) {
#pragma unroll
    for (int r = 0; r < 4; ++r) {
      const int lr = wr * 64 + i * 16 + quad * 4 + r;
      const int grow = rows_s[lr];
      if (grow < 0) continue;
      const float s0 = s0_s[lr];
#pragma unroll
      for (int j = 0; j < 4; ++j) {
        const float v = CLAMP1E4(s0 * (acc[i][j][r] + beb[j]));
        mid[(size_t)grow * HID + colj[j]] = (bf16_t)v;
      }
    }
  }
}

// ---------------------------------------------------------------------------
// res_gemm_p: reads Hperm (contiguous), RMW-scatters into mid[rowid].
// BK=64 + swizzled LDS.
// ---------------------------------------------------------------------------
__global__ __launch_bounds__(256) void res_gemm_p(
    const bf16_t* __restrict__ Hp, const bf16_t* __restrict__ Bt,
    const float* __restrict__ rB, const int* __restrict__ rowid,
    const float* __restrict__ s1p, bf16_t* __restrict__ mid) {
  __shared__ bf16_t As[128 * 64];
  __shared__ bf16_t Bs[128 * 64];

  const int tid = threadIdx.x, lane = tid & 63, w = tid >> 6;
  const int wr = w >> 1, wc = w & 1, quad = lane >> 4, l16 = lane & 15;
  const int m0 = blockIdx.x * 128, n0 = blockIdx.y * 128;
  const char* Ab = (const char*)Hp;
  const char* Bb = (const char*)Bt;

  size_t aoff[4], boff[4];
  int cb[4];
#pragma unroll
  for (int c = 0; c < 4; ++c) {
    cb[c] = (w * 4 + c) * 1024;
    const int o = cb[c] + lane * 16;
    const int row = o >> 7;
    const int kb = (o & 127) ^ ((row & 7) << 4);
    aoff[c] = (size_t)(m0 + row) * (HID * 2) + kb;
    boff[c] = (size_t)(n0 + row) * (HID * 2) + kb;
  }
  const int sw = (l16 & 7) << 3;

  const f32x4 fz = {0.f, 0.f, 0.f, 0.f};
  f32x4 acc[4][4];
#pragma unroll
  for (int i = 0; i < 4; ++i)
#pragma unroll
    for (int j = 0; j < 4; ++j) acc[i][j] = fz;

  for (int kt = 0; kt < HID / 64; ++kt) {
    __syncthreads();
#pragma unroll
    for (int c = 0; c < 4; ++c) {
      ASYNC16(Ab + aoff[c] + (size_t)kt * 128, (char*)As + cb[c]);
      ASYNC16(Bb + boff[c] + (size_t)kt * 128, (char*)Bs + cb[c]);
    }
    __syncthreads();

#pragma unroll
    for (int ks = 0; ks < 2; ++ks) {
      const int co = (ks * 32 + quad * 8) ^ sw;
      bf16x8 af[4], bfr[4];
#pragma unroll
      for (int i = 0; i < 4; ++i)
        af[i] = *(const bf16x8*)&As[(wr * 64 + i * 16 + l16) * 64 + co];
#pragma unroll
      for (int j = 0; j < 4; ++j)
        bfr[j] = *(const bf16x8*)&Bs[(wc * 64 + j * 16 + l16) * 64 + co];
#pragma unroll
      for (int i = 0; i < 4; ++i)
#pragma unroll
        for (int j = 0; j < 4; ++j)
          acc[i][j] = __builtin_amdgcn_mfma_f32_16x16x32_bf16(
              af[i], bfr[j], acc[i][j], 0, 0, 0);
    }
  }

  float rbb[4];
  int colj[4];
#pragma unroll
  for (int j = 0; j < 4; ++j) {
    colj[j] = n0 + wc * 64 + j * 16 + l16;
    rbb[j] = rB[colj[j]];
  }
#pragma unroll
  for (int i = 0; i < 4; ++i) {
#pragma unroll
    for (int r = 0; r < 4; ++r) {
      const int p = m0 + wr * 64 + i * 16 + quad * 4 + r;
      const int grow = rowid[p];
      const float s1 = s1p[p];
#pragma unroll
      for (int j = 0; j < 4; ++j) {
        const size_t ix = (size_t)grow * HID + colj[j];
        const float v =
            CLAMP1E4(s1 * (acc[i][j][r] + rbb[j]) + (float)mid[ix]);
        mid[ix] = (bf16_t)v;
      }
    }
  }
}

// ---------------------------------------------------------------------------
// dec: out = mid @ dec_W + dec_b; BK=64 + swizzled LDS; output dtype per flag.
// ---------------------------------------------------------------------------
__global__ __launch_bounds__(256) void dec_gemm(
    const bf16_t* __restrict__ A, const bf16_t* __restrict__ Bt,
    const float* __restrict__ bias, void* __restrict__ C,
    const int* __restrict__ flagp) {
  __shared__ bf16_t As[128 * 64];
  __shared__ bf16_t Bs[128 * 64];

  const int fl = *flagp;
  const int tid = threadIdx.x, lane = tid & 63, w = tid >> 6;
  const int wr = w >> 1, wc = w & 1, quad = lane >> 4, l16 = lane & 15;
  const int m0 = blockIdx.x * 128, n0 = blockIdx.y * 128;
  const char* Ab = (const char*)A;
  const char* Bb = (const char*)Bt;

  size_t aoff[4], boff[4];
  int cb[4];
#pragma unroll
  for (int c = 0; c < 4; ++c) {
    cb[c] = (w * 4 + c) * 1024;
    const int o = cb[c] + lane * 16;
    const int row = o >> 7;
    const int kb = (o & 127) ^ ((row & 7) << 4);
    aoff[c] = (size_t)(m0 + row) * (HID * 2) + kb;
    boff[c] = (size_t)(n0 + row) * (HID * 2) + kb;
  }
  const int sw = (l16 & 7) << 3;

  const f32x4 fz = {0.f, 0.f, 0.f, 0.f};
  f32x4 acc[4][4];
#pragma unroll
  for (int i = 0; i < 4; ++i)
#pragma unroll
    for (int j = 0; j < 4; ++j) acc[i][j] = fz;

  for (int kt = 0; kt < HID / 64; ++kt) {
    __syncthreads();
#pragma unroll
    for (int c = 0; c < 4; ++c) {
      ASYNC16(Ab + aoff[c] + (size_t)kt * 128, (char*)As + cb[c]);
      ASYNC16(Bb + boff[c] + (size_t)kt * 128, (char*)Bs + cb[c]);
    }
    __syncthreads();

#pragma unroll
    for (int ks = 0; ks < 2; ++ks) {
      const int co = (ks * 32 + quad * 8) ^ sw;
      bf16x8 af[4], bfr[4];
#pragma unroll
      for (int i = 0; i < 4; ++i)
        af[i] = *(const bf16x8*)&As[(wr * 64 + i * 16 + l16) * 64 + co];
#pragma unroll
      for (int j = 0; j < 4; ++j)
        bfr[j] = *(const bf16x8*)&Bs[(wc * 64 + j * 16 + l16) * 64 + co];
#pragma unroll
      for (int i = 0; i < 4; ++i)
#pragma unroll
        for (int j = 0; j < 4; ++j)
          acc[i][j] = __builtin_amdgcn_mfma_f32_16x16x32_bf16(
              af[i], bfr[j], acc[i][j], 0, 0, 0);
    }
  }

  float bb[4];
  int colj[4];
#pragma unroll
  for (int j = 0; j < 4; ++j) {
    colj[j] = n0 + wc * 64 + j * 16 + l16;
    bb[j] = bias[colj[j]];
  }
#pragma unroll
  for (int i = 0; i < 4; ++i) {
#pragma unroll
    for (int r = 0; r < 4; ++r) {
      const int row = m0 + wr * 64 + i * 16 + quad * 4 + r;
#pragma unroll
      for (int j = 0; j < 4; ++j) {
        const float v = CLAMP1E4(acc[i][j][r] + bb[j]);
        const size_t ix = (size_t)row * IN_DIM + colj[j];
        if (fl)
          ((float*)C)[ix] = v;
        else
          ((bf16_t*)C)[ix] = (bf16_t)v;
      }
    }
  }
}

// ---------------------------------------------------------------------------
// small-path fallbacks (BK=32, R1 behavior; used only if ws can't hold wTall)
// ---------------------------------------------------------------------------
__global__ __launch_bounds__(256) void bucket_rows(
    const int* __restrict__ eidx, int* __restrict__ curs,
    int* __restrict__ perm) {
  const int r = blockIdx.x * 256 + threadIdx.x;
  const int e = eidx[r];
  const int pos = atomicAdd(&curs[e], 1);
  perm[(size_t)e * N_TOK + pos] = r;
}

__global__ __launch_bounds__(256) void expert_gemm(
    const bf16_t* __restrict__ H, const bf16_t* __restrict__ wTe,
    const float* __restrict__ eBe, const int* __restrict__ permE,
    const int* __restrict__ cnt, int e, const float* __restrict__ s0g,
    bf16_t* __restrict__ mid) {
  __shared__ bf16_t As[128 * 32];
  __shared__ bf16_t Bs[128 * 32];
  __shared__ int rows_s[128];
  __shared__ float s0_s[128];

  const int cnte = cnt[e];
  const int lt = blockIdx.x;
  if (lt * 128 >= cnte) return;
  int nrows = cnte - lt * 128;
  if (nrows > 128) nrows = 128;

  const int tid = threadIdx.x, lane = tid & 63, w = tid >> 6;
  const int wr = w >> 1, wc = w & 1, quad = lane >> 4, l16 = lane & 15;

  if (tid < 128) {
    int grow = -1;
    float a0 = 0.f;
    if (tid < nrows) {
      grow = permE[lt * 128 + tid];
      a0 = s0g[grow];
    }
    rows_s[tid] = grow;
    s0_s[tid] = a0;
  }
  __syncthreads();

  const int n0 = blockIdx.y * 128;
  const char* Hb = (const char*)H;
  const char* Wb = (const char*)wTe;

  size_t aoff[2], boff[2];
  int cb[2];
#pragma unroll
  for (int c = 0; c < 2; ++c) {
    cb[c] = (w * 2 + c) * 1024;
    const int o = cb[c] + lane * 16;
    const int row = o >> 6, kb = o & 63;
    int gr = rows_s[row];
    if (gr < 0) gr = 0;
    aoff[c] = (size_t)gr * (HID * 2) + kb;
    boff[c] = (size_t)(n0 + row) * (HID * 2) + kb;
  }

  const f32x4 fz = {0.f, 0.f, 0.f, 0.f};
  f32x4 acc[4][4];
#pragma unroll
  for (int i = 0; i < 4; ++i)
#pragma unroll
    for (int j = 0; j < 4; ++j) acc[i][j] = fz;

  for (int kt = 0; kt < HID / 32; ++kt) {
    __syncthreads();
#pragma unroll
    for (int c = 0; c < 2; ++c) {
      ASYNC16(Hb + aoff[c] + (size_t)kt * 64, (char*)As + cb[c]);
      ASYNC16(Wb + boff[c] + (size_t)kt * 64, (char*)Bs + cb[c]);
    }
    __syncthreads();

    bf16x8 af[4], bfr[4];
#pragma unroll
    for (int i = 0; i < 4; ++i)
      af[i] = *(const bf16x8*)&As[(wr * 64 + i * 16 + l16) * 32 + quad * 8];
#pragma unroll
    for (int j = 0; j < 4; ++j)
      bfr[j] = *(const bf16x8*)&Bs[(wc * 64 + j * 16 + l16) * 32 + quad * 8];
#pragma unroll
    for (int i = 0; i < 4; ++i)
#pragma unroll
      for (int j = 0; j < 4; ++j)
        acc[i][j] = __builtin_amdgcn_mfma_f32_16x16x32_bf16(af[i], bfr[j],
                                                            acc[i][j], 0, 0, 0);
  }

  float beb[4];
  int colj[4];
#pragma unroll
  for (int j = 0; j < 4; ++j) {
    colj[j] = n0 + wc * 64 + j * 16 + l16;
    beb[j] = eBe[colj[j]];
  }
#pragma unroll
  for (int i = 0; i < 4; ++i) {
#pragma unroll
    for (int r = 0; r < 4; ++r) {
      const int lr = wr * 64 + i * 16 + quad * 4 + r;
      const int grow = rows_s[lr];
      if (grow < 0) continue;
      const float s0 = s0_s[lr];
#pragma unroll
      for (int j = 0; j < 4; ++j) {
        const float v = CLAMP1E4(s0 * (acc[i][j][r] + beb[j]));
        mid[(size_t)grow * HID + colj[j]] = (bf16_t)v;
      }
    }
  }
}

__global__ __launch_bounds__(256) void res_gemm(
    const bf16_t* __restrict__ H, const bf16_t* __restrict__ Bt,
    const float* __restrict__ rB, const float* __restrict__ s1g,
    bf16_t* __restrict__ mid) {
  __shared__ bf16_t As[128 * 32];
  __shared__ bf16_t Bs[128 * 32];

  const int tid = threadIdx.x, lane = tid & 63, w = tid >> 6;
  const int wr = w >> 1, wc = w & 1, quad = lane >> 4, l16 = lane & 15;
  const int m0 = blockIdx.x * 128, n0 = blockIdx.y * 128;
  const char* Ab = (const char*)H;
  const char* Bb = (const char*)Bt;

  size_t aoff[2], boff[2];
  int cb[2];
#pragma unroll
  for (int c = 0; c < 2; ++c) {
    cb[c] = (w * 2 + c) * 1024;
    const int o = cb[c] + lane * 16;
    const int row = o >> 6, kb = o & 63;
    aoff[c] = (size_t)(m0 + row) * (HID * 2) + kb;
    boff[c] = (size_t)(n0 + row) * (HID * 2) + kb;
  }

  const f32x4 fz = {0.f, 0.f, 0.f, 0.f};
  f32x4 acc[4][4];
#pragma unroll
  for (int i = 0; i < 4; ++i)
#pragma unroll
    for (int j = 0; j < 4; ++j) acc[i][j] = fz;

  for (int kt = 0; kt < HID / 32; ++kt) {
    __syncthreads();
#pragma unroll
    for (int c = 0; c < 2; ++c) {
      ASYNC16(Ab + aoff[c] + (size_t)kt * 64, (char*)As + cb[c]);
      ASYNC16(Bb + boff[c] + (size_t)kt * 64, (char*)Bs + cb[c]);
    }
    __syncthreads();

    bf16x8 af[4], bfr[4];
#pragma unroll
    for (int i = 0; i < 4; ++i)
      af[i] = *(const bf16x8*)&As[(wr * 64 + i * 16 + l16) * 32 + quad * 8];
#pragma unroll
    for (int j = 0; j < 4; ++j)
      bfr[j] = *(const bf16x8*)&Bs[(wc * 64 + j * 16 + l16) * 32 + quad * 8];
#pragma unroll
    for (int i = 0; i < 4; ++i)
#pragma unroll
      for (int j = 0; j < 4; ++j)
        acc[i][j] = __builtin_amdgcn_mfma_f32_16x16x32_bf16(af[i], bfr[j],
                                                            acc[i][j], 0, 0, 0);
  }

  float rbb[4];
  int colj[4];
#pragma unroll
  for (int j = 0; j < 4; ++j) {
    colj[j] = n0 + wc * 64 + j * 16 + l16;
    rbb[j] = rB[colj[j]];
  }
#pragma unroll
  for (int i = 0; i < 4; ++i) {
#pragma unroll
    for (int r = 0; r < 4; ++r) {
      const int row = m0 + wr * 64 + i * 16 + quad * 4 + r;
      const float s1 = s1g[row];
#pragma unroll
      for (int j = 0; j < 4; ++j) {
        const size_t ix = (size_t)row * HID + colj[j];
        const float v =
            CLAMP1E4(s1 * (acc[i][j][r] + rbb[j]) + (float)mid[ix]);
        mid[ix] = (bf16_t)v;
      }
    }
  }
}

// ---------------------------------------------------------------------------
extern "C" void kernel_launch(void* const* d_in, const int* in_sizes, int n_in,
                              void* d_out, int out_size, void* d_ws,
                              size_t ws_size, hipStream_t stream) {
  (void)in_sizes; (void)n_in;

  const void* x     = d_in[0];
  const void* encW  = d_in[1];
  const void* encB  = d_in[2];
  const void* gateW = d_in[3];
  const void* expW  = d_in[4];
  const void* expB  = d_in[5];
  const void* resW  = d_in[6];
  const void* resB  = d_in[7];
  const void* coefW = d_in[8];
  const void* coefB = d_in[9];
  const void* decW  = d_in[10];
  const void* decB  = d_in[11];

  // --- workspace layout: ~142MB base, +80MB wTall if available ---
  char* ws = (char*)d_ws;
  size_t o = 0;
  int*    flag  = (int*)(ws + o);    o += 256;
  int*    cnt   = (int*)(ws + o);    o += 256;   // cnt[0..7]; acnt@[8]; curs@[16..23]
  int*    acnt  = cnt + 8;
  int*    curs  = cnt + 16;
  float*  s0g   = (float*)(ws + o);  o += (size_t)N_TOK * 4;
  float*  s1g   = (float*)(ws + o);  o += (size_t)N_TOK * 4;
  float*  c0g   = (float*)(ws + o);  o += (size_t)N_TOK * 4;
  int*    eidx  = (int*)(ws + o);    o += (size_t)N_TOK * 4;
  int*    ambig = (int*)(ws + o);    o += (size_t)N_TOK * 4;
  int*    permfl= (int*)(ws + o);    o += (size_t)N_TOK * 4;
  int*    rowid = (int*)(ws + o);    o += (size_t)N_TOK * 4;
  float*  s0p   = (float*)(ws + o);  o += (size_t)N_TOK * 4;
  float*  s1p   = (float*)(ws + o);  o += (size_t)N_TOK * 4;
  int*    perm  = (int*)(ws + o);    o += (size_t)NEXP * N_TOK * 4;  // small path
  float*  encBf = (float*)(ws + o);  o += HID * 4;
  float*  expBf = (float*)(ws + o);  o += (size_t)NEXP * HID * 4;
  float*  resBf = (float*)(ws + o);  o += HID * 4;
  float*  decBf = (float*)(ws + o);  o += IN_DIM * 4;
  float*  coefBf= (float*)(ws + o);  o += 256;
  bf16_t* gWb   = (bf16_t*)(ws + o); o += (size_t)HID * 8 * 2;
  bf16_t* cWb   = (bf16_t*)(ws + o); o += (size_t)HID * 2 * 2;
  o = (o + 255) & ~(size_t)255;
  bf16_t* bufA  = (bf16_t*)(ws + o); o += (size_t)N_TOK * HID * 2;   // 64 MB
  bf16_t* bufB  = (bf16_t*)(ws + o); o += (size_t)N_TOK * HID * 2;   // 64 MB
  bf16_t* wT    = (bf16_t*)(ws + o); o += (size_t)HID * HID * 2;     // 8 MB
  const size_t needed_small = o;
  const size_t S = (size_t)HID * HID;  // elements per wTall slot
  bf16_t* wTall = (bf16_t*)(ws + o);   // slots 0..7 experts, 8 res, 9 dec
  const size_t needed_big = o + 10 * S * 2;                          // +80 MB

  // pglg (f64 rescue partials, 1024 rows x 32 slices x 8 experts = 2MB)
  // lives in bufB: free window between enc_gemm (xbf dead) and gather_rows
  // (big path) / expert_gemm mid writes (small path).
  double* pglg = (double*)bufB;

  // buffer roles:
  //  big:   xbf=bufB -> enc writes H=bufA -> [rescue pglg in bufB] ->
  //         gather writes Hperm=bufB -> expert writes mid=bufA -> res RMWs
  //         mid -> dec reads bufA
  //  small: xbf=bufB -> enc writes H=bufA -> [rescue pglg in bufB] ->
  //         experts write mid=bufB -> dec reads bufB
  bf16_t* hbuf  = bufA;
  bf16_t* xbf   = bufB;

  if (ws_size < needed_small) {
    const float v = (float)(ws_size >> 20);  // report budget in MB
    fill_bf16<<<dim3((out_size + 255) / 256), 256, 0, stream>>>(
        (bf16_t*)d_out, v, out_size);
    return;
  }
  const bool big = ws_size >= needed_big;

  detect_dtype<<<1, 256, 0, stream>>>((const ushort_t*)x, flag);
  hipMemsetAsync(cnt, 0, 256, stream);

  // --- normalize inputs ---
  cvt_to_bf16_x4<<<dim3(N_TOK * IN_DIM / 4 / 256), 256, 0, stream>>>(
      x, xbf, N_TOK * IN_DIM / 4, flag);
  cvt_small<<<dim3(64, 7), 256, 0, stream>>>(encB, expB, resB, decB, coefB,
                                             gateW, coefW, encBf, expBf, resBf,
                                             decBf, coefBf, gWb, cWb, flag);

  const dim3 tb(32, 8, 1);

  // --- weight prep ---
  transpose_cvt<<<dim3(HID / 32, IN_DIM / 32, 1), tb, 0, stream>>>(
      encW, (ushort_t*)wT, IN_DIM, HID, 0, flag, 0, 0);
  if (big) {
    transpose_cvt<<<dim3(HID / 32, HID / 32, NEXP), tb, 0, stream>>>(
        expW, (ushort_t*)wTall, HID, HID, 0, flag, S, S);
    transpose_cvt<<<dim3(HID / 32, HID / 32, 1), tb, 0, stream>>>(
        resW, (ushort_t*)(wTall + 8 * S), HID, HID, 0, flag, 0, 0);
    transpose_cvt<<<dim3(IN_DIM / 32, HID / 32, 1), tb, 0, stream>>>(
        decW, (ushort_t*)(wTall + 9 * S), HID, IN_DIM, 0, flag, 0, 0);
  }

  // --- enc + gating ---
  enc_gemm<<<dim3(N_TOK / 128, HID / 128), 256, 0, stream>>>(xbf, wT, encBf,
                                                             hbuf);
  gate_from_h<<<dim3(N_TOK / 16), 256, 0, stream>>>(
      hbuf, gWb, cWb, coefBf, s0g, s1g, c0g, eidx, ambig, acnt, cnt);
  // tiled f64 rescue: 8 rows x 64 cols x 4 k-quarters per block (W-reuse AND
  // 960 active blocks), fixed-order combine
  rescue_tile2<<<dim3(128, 32), 256, 0, stream>>>(x, encW, encBf, gateW, flag,
                                                  ambig, acnt, pglg);
  rescue_final<<<dim3(1024), 64, 0, stream>>>(ambig, acnt, c0g, pglg, s0g,
                                              eidx, cnt);
  // overflow guard for acnt > 1024 (whole-row legacy path; normally no-op)
  rescue_rows<<<dim3(N_TOK - 1024), 256, 0, stream>>>(
      x, encW, encBf, gateW, flag, ambig, acnt, c0g, s0g, eidx, cnt, 1024);

  if (big) {
    bf16_t* Hperm = bufB;  // pglg consumed by rescue_final before gather
    bf16_t* mid   = bufA;  // H dead after gather
    place_rows<<<dim3(N_TOK / 256), 256, 0, stream>>>(eidx, cnt, curs, permfl);
    gather_rows<<<dim3(N_TOK / 4), 256, 0, stream>>>(hbuf, permfl, s0g, s1g,
                                                     Hperm, rowid, s0p, s1p);
    expert_gemm_t<<<dim3(136, HID / 128), 256, 0, stream>>>(
        Hperm, wTall, S, expBf, cnt, rowid, s0p, mid);
    res_gemm_p<<<dim3(N_TOK / 128, HID / 128), 256, 0, stream>>>(
        Hperm, wTall + 8 * S, resBf, rowid, s1p, mid);
    dec_gemm<<<dim3(N_TOK / 128, IN_DIM / 128), 256, 0, stream>>>(
        mid, wTall + 9 * S, decBf, d_out, flag);
  } else {
    // --- fallback: serial per-expert path (R1 behavior) ---
    bf16_t* mid = bufB;  // pglg consumed before expert writes
    bucket_rows<<<dim3(N_TOK / 256), 256, 0, stream>>>(eidx, curs, perm);
    for (int e = 0; e < NEXP; ++e) {
      transpose_cvt<<<dim3(HID / 32, HID / 32, 1), tb, 0, stream>>>(
          expW, (ushort_t*)wT, HID, HID, (size_t)e * HID * HID, flag, 0, 0);
      expert_gemm<<<dim3(N_TOK / 128, HID / 128), 256, 0, stream>>>(
          hbuf, wT, expBf + (size_t)e * HID, perm + (size_t)e * N_TOK, cnt, e,
          s0g, mid);
    }
    transpose_cvt<<<dim3(HID / 32, HID / 32, 1), tb, 0, stream>>>(
        resW, (ushort_t*)wT, HID, HID, 0, flag, 0, 0);
    res_gemm<<<dim3(N_TOK / 128, HID / 128), 256, 0, stream>>>(hbuf, wT, resBf,
                                                               s1g, mid);
    transpose_cvt<<<dim3(IN_DIM / 32, HID / 32, 1), tb, 0, stream>>>(
        decW, (ushort_t*)wT, HID, IN_DIM, 0, flag, 0, 0);
    dec_gemm<<<dim3(N_TOK / 128, IN_DIM / 128), 256, 0, stream>>>(
        mid, wT, decBf, d_out, flag);
  }
}

// Round 9
// 1329.819 us; speedup vs baseline: 1.3204x; 1.0123x over previous
//
#include <hip/hip_runtime.h>

// ---------------------------------------------------------------------------
// MoE Autoencoder, MI355X (gfx950). DTYPE-ADAPTIVE (f32 or bf16 inputs).
// R9 changes vs R8 (1346us):
//  - expert_gemm_t was top at 255us: MfmaUtil 23% (= its 59us MFMA floor,
//    pipe itself fine) but FETCH 444MB vs 128MB compulsory. Cause: x-fastest
//    dispatch swept all 136 token-tiles per col-row -> re-read 64MB Hperm
//    x16 and thrashed L3. Fix: COLUMN-FAST grids on all four big GEMMs --
//    consecutive blocks now share one 512KB A-panel (L2-hot) and walk one
//    expert's W in consecutive slices (~8.5MB reuse window).
//  - Everything else identical to R8 (rescue_tile2, TAU 3e-3, BK=64+swizzle).
// ---------------------------------------------------------------------------

#define N_TOK 16384
#define IN_DIM 1024
#define HID 2048
#define NEXP 8
#define TAU 3.0e-3f
#define RROWS 8

typedef __bf16 bf16_t;
typedef __bf16 bf16x8 __attribute__((ext_vector_type(8)));
typedef __bf16 bf16x4v __attribute__((ext_vector_type(4)));
typedef float f32x4 __attribute__((ext_vector_type(4)));
typedef unsigned short ushort_t;

#define CLAMP1E4(v) fmaxf(fminf((v), 1.0e4f), -1.0e4f)

#define ASYNC16(gp, lp)                                                        \
  __builtin_amdgcn_global_load_lds(                                            \
      (const __attribute__((address_space(1))) void*)(gp),                     \
      (__attribute__((address_space(3))) void*)(lp), 16, 0, 0)

static __device__ inline ushort_t b2u(bf16_t v) {
  union { bf16_t b; ushort_t u; } x; x.b = v; return x.u;
}

// ---------------------------------------------------------------------------
__global__ __launch_bounds__(256) void fill_bf16(bf16_t* __restrict__ p,
                                                 float v, int n) {
  const int i = blockIdx.x * 256 + threadIdx.x;
  if (i < n) p[i] = (bf16_t)v;
}

// ---------------------------------------------------------------------------
// flag=1  <=>  raw data is f32 (reading it as bf16 yields wild exponents)
// ---------------------------------------------------------------------------
__global__ __launch_bounds__(256) void detect_dtype(
    const ushort_t* __restrict__ xr, int* __restrict__ flag) {
  __shared__ int s_bad;
  if (threadIdx.x == 0) s_bad = 0;
  __syncthreads();
  int bad = 0;
  for (int i = threadIdx.x; i < 4096; i += 256) {
    const int e = (xr[i] >> 7) & 0xFF;
    if (e >= 0xC0) bad = 1;  // |v| >= 2^65: impossible for real bf16 data
  }
  if (__any(bad) && (threadIdx.x & 63) == 0) atomicOr(&s_bad, 1);
  __syncthreads();
  if (threadIdx.x == 0) *flag = s_bad;
}

// ---------------------------------------------------------------------------
// vectorized x4 conversion for the big x buffer
__global__ __launch_bounds__(256) void cvt_to_bf16_x4(
    const void* __restrict__ src, bf16_t* __restrict__ dst, int n4,
    const int* __restrict__ flagp) {
  const int f = *flagp;
  const int i = blockIdx.x * 256 + threadIdx.x;
  if (i >= n4) return;
  bf16x4v o;
  if (f) {
    const f32x4 v = ((const f32x4*)src)[i];
    o[0] = (bf16_t)v[0]; o[1] = (bf16_t)v[1];
    o[2] = (bf16_t)v[2]; o[3] = (bf16_t)v[3];
  } else {
    o = ((const bf16x4v*)src)[i];
  }
  ((bf16x4v*)dst)[i] = o;
}

// ---------------------------------------------------------------------------
// all small conversions in one launch. blockIdx.y = segment.
// ---------------------------------------------------------------------------
__global__ __launch_bounds__(256) void cvt_small(
    const void* __restrict__ encB, const void* __restrict__ expB,
    const void* __restrict__ resB, const void* __restrict__ decB,
    const void* __restrict__ coefB, const void* __restrict__ gateW,
    const void* __restrict__ coefW, float* __restrict__ encBf,
    float* __restrict__ expBf, float* __restrict__ resBf,
    float* __restrict__ decBf, float* __restrict__ coefBf,
    bf16_t* __restrict__ gWb, bf16_t* __restrict__ cWb,
    const int* __restrict__ flagp) {
  const int f = *flagp;
  const int i = blockIdx.x * 256 + threadIdx.x;
  const int seg = blockIdx.y;
  const void* src;
  int n;
  switch (seg) {
    case 0: src = encB;  n = HID; break;
    case 1: src = expB;  n = NEXP * HID; break;
    case 2: src = resB;  n = HID; break;
    case 3: src = decB;  n = IN_DIM; break;
    case 4: src = coefB; n = 2; break;
    case 5: src = gateW; n = HID * 8; break;
    default: src = coefW; n = HID * 2; break;
  }
  if (i >= n) return;
  const float v = f ? ((const float*)src)[i] : (float)((const bf16_t*)src)[i];
  switch (seg) {
    case 0: encBf[i] = v; break;
    case 1: expBf[i] = v; break;
    case 2: resBf[i] = v; break;
    case 3: decBf[i] = v; break;
    case 4: coefBf[i] = v; break;
    case 5: gWb[i] = (bf16_t)v; break;
    default: cWb[i] = (bf16_t)v; break;
  }
}

// ---------------------------------------------------------------------------
// transpose + convert: src[R][C] (f32 or bf16 per flag) -> dst[C][R] bf16.
// ---------------------------------------------------------------------------
__global__ __launch_bounds__(256) void transpose_cvt(
    const void* __restrict__ src0, ushort_t* __restrict__ dst, int R, int C,
    size_t elem_off, const int* __restrict__ flagp, size_t src_zstride,
    size_t dst_zstride) {
  __shared__ ushort_t t[32][33];
  const int f = *flagp;
  const size_t eoff = elem_off + (size_t)blockIdx.z * src_zstride;
  dst += (size_t)blockIdx.z * dst_zstride;
  const int c0 = blockIdx.x * 32, r0 = blockIdx.y * 32;
  const int tx = threadIdx.x, ty = threadIdx.y;
  if (f) {
    const float* s = (const float*)src0 + eoff;
#pragma unroll
    for (int i = 0; i < 4; ++i)
      t[ty + i * 8][tx] =
          b2u((bf16_t)s[(size_t)(r0 + ty + i * 8) * C + c0 + tx]);
  } else {
    const ushort_t* s = (const ushort_t*)src0 + eoff;
#pragma unroll
    for (int i = 0; i < 4; ++i)
      t[ty + i * 8][tx] = s[(size_t)(r0 + ty + i * 8) * C + c0 + tx];
  }
  __syncthreads();
#pragma unroll
  for (int i = 0; i < 4; ++i)
    dst[(size_t)(c0 + ty + i * 8) * R + r0 + tx] = t[tx][ty + i * 8];
}

// ---------------------------------------------------------------------------
// Shared BK=64 GEMM geometry (128x128 tile, [128][64] bf16 LDS per matrix,
// swizzled: achieved by permuting the per-lane GLOBAL source and XOR-ing the
// ds_read column. 2 K-sub-steps of 16 MFMA each. ALL grids are COLUMN-FAST:
// blockIdx.x = output-column tile, blockIdx.y = token/row tile, so
// consecutive blocks share one A-panel (L2-hot) and walk W consecutively.
// ---------------------------------------------------------------------------

// enc: h = relu(x @ enc_W + b) (bf16). K = IN_DIM. grid (HID/128, N_TOK/128).
__global__ __launch_bounds__(256) void enc_gemm(
    const bf16_t* __restrict__ A, const bf16_t* __restrict__ Bt,
    const float* __restrict__ bias, bf16_t* __restrict__ H) {
  __shared__ bf16_t As[128 * 64];
  __shared__ bf16_t Bs[128 * 64];

  const int tid = threadIdx.x, lane = tid & 63, w = tid >> 6;
  const int wr = w >> 1, wc = w & 1, quad = lane >> 4, l16 = lane & 15;
  const int m0 = blockIdx.y * 128, n0 = blockIdx.x * 128;  // col-fast
  const char* Ab = (const char*)A;
  const char* Bb = (const char*)Bt;
  const size_t lda = (size_t)IN_DIM * 2;

  const f32x4 fz = {0.f, 0.f, 0.f, 0.f};
  f32x4 acc[4][4];
#pragma unroll
  for (int i = 0; i < 4; ++i)
#pragma unroll
    for (int j = 0; j < 4; ++j) acc[i][j] = fz;

  size_t aoff[4], boff[4];
  int cb[4];
#pragma unroll
  for (int c = 0; c < 4; ++c) {
    cb[c] = (w * 4 + c) * 1024;
    const int o = cb[c] + lane * 16;
    const int row = o >> 7;
    const int kb = (o & 127) ^ ((row & 7) << 4);  // pre-swizzled source
    aoff[c] = (size_t)(m0 + row) * lda + kb;
    boff[c] = (size_t)(n0 + row) * lda + kb;
  }
  const int sw = (l16 & 7) << 3;  // element-space read swizzle

  for (int kt = 0; kt < IN_DIM / 64; ++kt) {
    __syncthreads();
#pragma unroll
    for (int c = 0; c < 4; ++c) {
      ASYNC16(Ab + aoff[c] + (size_t)kt * 128, (char*)As + cb[c]);
      ASYNC16(Bb + boff[c] + (size_t)kt * 128, (char*)Bs + cb[c]);
    }
    __syncthreads();

#pragma unroll
    for (int ks = 0; ks < 2; ++ks) {
      const int co = (ks * 32 + quad * 8) ^ sw;
      bf16x8 af[4], bfr[4];
#pragma unroll
      for (int i = 0; i < 4; ++i)
        af[i] = *(const bf16x8*)&As[(wr * 64 + i * 16 + l16) * 64 + co];
#pragma unroll
      for (int j = 0; j < 4; ++j)
        bfr[j] = *(const bf16x8*)&Bs[(wc * 64 + j * 16 + l16) * 64 + co];
#pragma unroll
      for (int i = 0; i < 4; ++i)
#pragma unroll
        for (int j = 0; j < 4; ++j)
          acc[i][j] = __builtin_amdgcn_mfma_f32_16x16x32_bf16(
              af[i], bfr[j], acc[i][j], 0, 0, 0);
    }
  }

  float bj[4];
  int colj[4];
#pragma unroll
  for (int j = 0; j < 4; ++j) {
    colj[j] = n0 + wc * 64 + j * 16 + l16;
    bj[j] = bias[colj[j]];
  }

#pragma unroll
  for (int i = 0; i < 4; ++i) {
#pragma unroll
    for (int r = 0; r < 4; ++r) {
      const int row = m0 + wr * 64 + i * 16 + quad * 4 + r;
#pragma unroll
      for (int j = 0; j < 4; ++j) {
        const float v = fminf(fmaxf(acc[i][j][r] + bj[j], 0.f), 1.0e4f);
        H[(size_t)row * HID + colj[j]] = (bf16_t)v;
      }
    }
  }
}

// ---------------------------------------------------------------------------
// gate_from_h: one wave per 4 rows; gate/coef logits + softmax/argmax;
// counts per expert; ambiguous rows -> rescue list.
// ---------------------------------------------------------------------------
__global__ __launch_bounds__(256) void gate_from_h(
    const bf16_t* __restrict__ H, const bf16_t* __restrict__ gW,
    const bf16_t* __restrict__ cW, const float* __restrict__ coefBf,
    float* __restrict__ s0g, float* __restrict__ s1g, float* __restrict__ c0g,
    int* __restrict__ eidx, int* __restrict__ ambig, int* __restrict__ acnt,
    int* __restrict__ cnt) {
  const int tid = threadIdx.x, lane = tid & 63, w = tid >> 6;
  const int r0 = blockIdx.x * 16 + w * 4;  // 4 waves * 4 rows per block

  float acc[4][10];
#pragma unroll
  for (int g = 0; g < 4; ++g)
#pragma unroll
    for (int o = 0; o < 10; ++o) acc[g][o] = 0.f;

#pragma unroll
  for (int it = 0; it < HID / 512; ++it) {  // 4 iterations
    const int h0 = it * 512 + lane * 8;
    bf16x8 hv[4];
#pragma unroll
    for (int g = 0; g < 4; ++g)
      hv[g] = *(const bf16x8*)(H + (size_t)(r0 + g) * HID + h0);
    const bf16_t* gp = gW + (size_t)h0 * 8;
    const bf16_t* cp = cW + (size_t)h0 * 2;
    bf16x8 cc0 = *(const bf16x8*)(cp);
    bf16x8 cc1 = *(const bf16x8*)(cp + 8);
#pragma unroll
    for (int k = 0; k < 8; ++k) {
      const bf16x8 gk = *(const bf16x8*)(gp + k * 8);
      const float ck0 = (k < 4) ? (float)cc0[(k & 3) * 2]
                                : (float)cc1[(k & 3) * 2];
      const float ck1 = (k < 4) ? (float)cc0[(k & 3) * 2 + 1]
                                : (float)cc1[(k & 3) * 2 + 1];
#pragma unroll
      for (int g = 0; g < 4; ++g) {
        const float v = (float)hv[g][k];
#pragma unroll
        for (int o = 0; o < 8; ++o) acc[g][o] += v * (float)gk[o];
        acc[g][8] += v * ck0;
        acc[g][9] += v * ck1;
      }
    }
  }

#pragma unroll
  for (int m = 1; m < 64; m <<= 1)
#pragma unroll
    for (int g = 0; g < 4; ++g)
#pragma unroll
      for (int o = 0; o < 10; ++o) acc[g][o] += __shfl_xor(acc[g][o], m);

  if (lane == 0) {
#pragma unroll
    for (int g = 0; g < 4; ++g) {
      const int r = r0 + g;
      float lv[8];
#pragma unroll
      for (int e = 0; e < 8; ++e) lv[e] = acc[g][e];
      float mx = lv[0];
      int idx = 0;
#pragma unroll
      for (int e = 1; e < 8; ++e)
        if (lv[e] > mx) { mx = lv[e]; idx = e; }
      float s2 = -1.0e30f;
#pragma unroll
      for (int e = 0; e < 8; ++e)
        if (e != idx) s2 = fmaxf(s2, lv[e]);
      float s = 0.f;
#pragma unroll
      for (int e = 0; e < 8; ++e) s += expf(lv[e] - mx);
      const float gate = 1.f / s;
      const float c0 = acc[g][8] + coefBf[0], c1 = acc[g][9] + coefBf[1];
      const float cm = fmaxf(c0, c1);
      const float e0 = expf(c0 - cm), e1 = expf(c1 - cm);
      const float inv = 1.f / (e0 + e1);
      const float p0 = e0 * inv;
      c0g[r] = p0;
      s1g[r] = e1 * inv;
      s0g[r] = gate * p0;
      eidx[r] = idx;
      atomicAdd(&cnt[idx], 1);
      if (mx - s2 < TAU) {
        const int p = atomicAdd(acnt, 1);
        ambig[p] = r;
      }
    }
  }
}

// ---------------------------------------------------------------------------
// rescue_tile2: grid (128, 32). Block (t, slice) = 8 amb rows x 64 cols.
// 256 threads = 64 cols (c) x 4 k-quarters (q). W-reuse (8 rows per W-slice
// read) AND 960 active blocks. Fixed-order combine -> deterministic.
// ---------------------------------------------------------------------------
__global__ __launch_bounds__(256) void rescue_tile2(
    const void* __restrict__ xraw, const void* __restrict__ encWraw,
    const float* __restrict__ encBf, const void* __restrict__ gateWraw,
    const int* __restrict__ flagp, const int* __restrict__ ambig,
    const int* __restrict__ acnt, double* __restrict__ pglg) {
  const int an0 = *acnt;
  const int an = an0 < 1024 ? an0 : 1024;  // tiled path covers first 1024
  const int i0 = blockIdx.x * RROWS;
  if (i0 >= an) return;
  int nr = an - i0;
  if (nr > RROWS) nr = RROWS;
  const int slice = blockIdx.y;
  const int f = *flagp;
  const int tid = threadIdx.x;
  const int c = tid & 63, q = tid >> 6;
  const int j = slice * 64 + c;  // this thread's h-column
  const int kb = q * 256;       // this thread's k-quarter

  __shared__ int rows_sh[RROWS];
  __shared__ float xs[RROWS][IN_DIM];   // 32 KB
  __shared__ double hp[4][RROWS][64];   // 16 KB: q, r, c

  if (tid < RROWS) rows_sh[tid] = ambig[i0 + (tid < nr ? tid : 0)];
  __syncthreads();

  for (int r = 0; r < RROWS; ++r) {
    const int row = rows_sh[r];
    if (f) {
      const float* xp = (const float*)xraw + (size_t)row * IN_DIM;
      for (int k = tid; k < IN_DIM; k += 256) xs[r][k] = xp[k];
    } else {
      const bf16_t* xp = (const bf16_t*)xraw + (size_t)row * IN_DIM;
      for (int k = tid; k < IN_DIM; k += 256) xs[r][k] = (float)xp[k];
    }
  }
  __syncthreads();

  double hacc[RROWS];
#pragma unroll
  for (int r = 0; r < RROWS; ++r) hacc[r] = 0.0;

  if (f) {
    const float* W = (const float*)encWraw + j;
    for (int k0 = 0; k0 < 256; k0 += 8) {
      double wd[8];
#pragma unroll
      for (int kk = 0; kk < 8; ++kk)
        wd[kk] = (double)W[(size_t)(kb + k0 + kk) * HID];
#pragma unroll
      for (int r = 0; r < RROWS; ++r) {
        const f32x4 xa = *(const f32x4*)&xs[r][kb + k0];
        const f32x4 xb2 = *(const f32x4*)&xs[r][kb + k0 + 4];
        double a = hacc[r];
        a += (double)xa[0] * wd[0];
        a += (double)xa[1] * wd[1];
        a += (double)xa[2] * wd[2];
        a += (double)xa[3] * wd[3];
        a += (double)xb2[0] * wd[4];
        a += (double)xb2[1] * wd[5];
        a += (double)xb2[2] * wd[6];
        a += (double)xb2[3] * wd[7];
        hacc[r] = a;
      }
    }
  } else {
    const bf16_t* W = (const bf16_t*)encWraw + j;
    for (int k0 = 0; k0 < 256; k0 += 8) {
      double wd[8];
#pragma unroll
      for (int kk = 0; kk < 8; ++kk)
        wd[kk] = (double)(float)W[(size_t)(kb + k0 + kk) * HID];
#pragma unroll
      for (int r = 0; r < RROWS; ++r) {
        const f32x4 xa = *(const f32x4*)&xs[r][kb + k0];
        const f32x4 xb2 = *(const f32x4*)&xs[r][kb + k0 + 4];
        double a = hacc[r];
        a += (double)xa[0] * wd[0];
        a += (double)xa[1] * wd[1];
        a += (double)xa[2] * wd[2];
        a += (double)xa[3] * wd[3];
        a += (double)xb2[0] * wd[4];
        a += (double)xb2[1] * wd[5];
        a += (double)xb2[2] * wd[6];
        a += (double)xb2[3] * wd[7];
        hacc[r] = a;
      }
    }
  }

#pragma unroll
  for (int r = 0; r < RROWS; ++r) hp[q][r][c] = hacc[r];
  __syncthreads();

  if (q == 0) {  // wave 0 exactly (tids 0..63)
    double gv[8];
    if (f) {
      const float* g = (const float*)gateWraw + (size_t)j * 8;
#pragma unroll
      for (int e = 0; e < 8; ++e) gv[e] = (double)g[e];
    } else {
      const bf16_t* g = (const bf16_t*)gateWraw + (size_t)j * 8;
#pragma unroll
      for (int e = 0; e < 8; ++e) gv[e] = (double)(float)g[e];
    }
    const double bj = (double)encBf[j];
    for (int r = 0; r < RROWS; ++r) {
      const double h =
          hp[0][r][c] + hp[1][r][c] + hp[2][r][c] + hp[3][r][c] + bj;
      double lg[8];
#pragma unroll
      for (int e = 0; e < 8; ++e) lg[e] = (h > 0.0) ? h * gv[e] : 0.0;
#pragma unroll
      for (int m = 1; m < 64; m <<= 1)
#pragma unroll
        for (int e = 0; e < 8; ++e) lg[e] += __shfl_xor(lg[e], m);
      if (c == 0 && r < nr) {
#pragma unroll
        for (int e = 0; e < 8; ++e)
          pglg[((size_t)(i0 + r) * 32 + slice) * 8 + e] = lg[e];
      }
    }
  }
}

// ---------------------------------------------------------------------------
// rescue_final: sums the 32 slice-partials per row in FIXED order (f64),
// argmax + softmax, updates s0g/eidx/cnt.
// ---------------------------------------------------------------------------
__global__ __launch_bounds__(64) void rescue_final(
    const int* __restrict__ ambig, const int* __restrict__ acnt,
    const float* __restrict__ c0g, const double* __restrict__ pglg,
    float* __restrict__ s0g, int* __restrict__ eidx, int* __restrict__ cnt) {
  const int i = blockIdx.x;
  if (i >= *acnt || threadIdx.x != 0) return;
  const int r = ambig[i];
  double t[8];
#pragma unroll
  for (int e = 0; e < 8; ++e) t[e] = 0.0;
  for (int s = 0; s < 32; ++s) {
#pragma unroll
    for (int e = 0; e < 8; ++e) t[e] += pglg[((size_t)i * 32 + s) * 8 + e];
  }
  double m = t[0];
  int idx = 0;
#pragma unroll
  for (int e = 1; e < 8; ++e)
    if (t[e] > m) { m = t[e]; idx = e; }
  double s = 0.0;
#pragma unroll
  for (int e = 0; e < 8; ++e) s += exp(t[e] - m);
  s0g[r] = (float)((1.0 / s) * (double)c0g[r]);
  const int old = eidx[r];
  if (idx != old) {
    atomicSub(&cnt[old], 1);
    atomicAdd(&cnt[idx], 1);
    eidx[r] = idx;
  }
}

// ---------------------------------------------------------------------------
// rescue_rows (legacy whole-row, ioff-based): guards the acnt>1024 overflow
// of the tiled path (normally a no-op).
// ---------------------------------------------------------------------------
__global__ __launch_bounds__(256) void rescue_rows(
    const void* __restrict__ xraw, const void* __restrict__ encWraw,
    const float* __restrict__ encBf, const void* __restrict__ gateWraw,
    const int* __restrict__ flagp, const int* __restrict__ ambig,
    const int* __restrict__ acnt, const float* __restrict__ c0g,
    float* __restrict__ s0g, int* __restrict__ eidx, int* __restrict__ cnt,
    int ioff) {
  const int i = blockIdx.x + ioff;
  if (i >= *acnt) return;
  const int r = ambig[i];
  const int f = *flagp;
  const int tid = threadIdx.x;

  __shared__ float xs[IN_DIM];
  if (f) {
    const float* xp = (const float*)xraw + (size_t)r * IN_DIM;
    for (int k = tid; k < IN_DIM; k += 256) xs[k] = xp[k];
  } else {
    const bf16_t* xp = (const bf16_t*)xraw + (size_t)r * IN_DIM;
    for (int k = tid; k < IN_DIM; k += 256) xs[k] = (float)xp[k];
  }
  __syncthreads();

  double hacc[8] = {0, 0, 0, 0, 0, 0, 0, 0};
  if (f) {
    const float* W = (const float*)encWraw;
    for (int k0 = 0; k0 < IN_DIM; k0 += 8) {
      float wv[8][8];
#pragma unroll
      for (int kk = 0; kk < 8; ++kk) {
        const float* Wr = W + (size_t)(k0 + kk) * HID + tid;
#pragma unroll
        for (int jj = 0; jj < 8; ++jj) wv[kk][jj] = Wr[jj * 256];
      }
#pragma unroll
      for (int kk = 0; kk < 8; ++kk) {
        const double xv = (double)xs[k0 + kk];
#pragma unroll
        for (int jj = 0; jj < 8; ++jj) hacc[jj] += xv * (double)wv[kk][jj];
      }
    }
  } else {
    const bf16_t* W = (const bf16_t*)encWraw;
    for (int k0 = 0; k0 < IN_DIM; k0 += 8) {
      float wv[8][8];
#pragma unroll
      for (int kk = 0; kk < 8; ++kk) {
        const bf16_t* Wr = W + (size_t)(k0 + kk) * HID + tid;
#pragma unroll
        for (int jj = 0; jj < 8; ++jj) wv[kk][jj] = (float)Wr[jj * 256];
      }
#pragma unroll
      for (int kk = 0; kk < 8; ++kk) {
        const double xv = (double)xs[k0 + kk];
#pragma unroll
        for (int jj = 0; jj < 8; ++jj) hacc[jj] += xv * (double)wv[kk][jj];
      }
    }
  }

  double lg[8] = {0, 0, 0, 0, 0, 0, 0, 0};
#pragma unroll
  for (int jj = 0; jj < 8; ++jj) {
    const int j = tid + jj * 256;
    double h = hacc[jj] + (double)encBf[j];
    if (h > 0.0) {
      if (f) {
        const float* g = (const float*)gateWraw + (size_t)j * 8;
#pragma unroll
        for (int e = 0; e < 8; ++e) lg[e] += h * (double)g[e];
      } else {
        const bf16_t* g = (const bf16_t*)gateWraw + (size_t)j * 8;
#pragma unroll
        for (int e = 0; e < 8; ++e) lg[e] += h * (double)(float)g[e];
      }
    }
  }
#pragma unroll
  for (int m = 1; m < 64; m <<= 1)
#pragma unroll
    for (int e = 0; e < 8; ++e) lg[e] += __shfl_xor(lg[e], m);

  __shared__ double red[4][8];
  const int w = tid >> 6, lane = tid & 63;
  if (lane == 0)
#pragma unroll
    for (int e = 0; e < 8; ++e) red[w][e] = lg[e];
  __syncthreads();
  if (tid == 0) {
    double t[8];
#pragma unroll
    for (int e = 0; e < 8; ++e)
      t[e] = red[0][e] + red[1][e] + red[2][e] + red[3][e];
    double m = t[0];
    int idx = 0;
#pragma unroll
    for (int e = 1; e < 8; ++e)
      if (t[e] > m) { m = t[e]; idx = e; }
    double s = 0.0;
#pragma unroll
    for (int e = 0; e < 8; ++e) s += exp(t[e] - m);
    s0g[r] = (float)((1.0 / s) * (double)c0g[r]);
    const int old = eidx[r];
    if (idx != old) {
      atomicSub(&cnt[old], 1);
      atomicAdd(&cnt[idx], 1);
      eidx[r] = idx;
    }
  }
}

// ---------------------------------------------------------------------------
__global__ __launch_bounds__(256) void place_rows(
    const int* __restrict__ eidx, const int* __restrict__ cnt,
    int* __restrict__ curs, int* __restrict__ permflat) {
  const int r = blockIdx.x * 256 + threadIdx.x;
  const int e = eidx[r];
  int prefix = 0;
  for (int ee = 0; ee < NEXP; ++ee)
    if (ee < e) prefix += cnt[ee];
  const int pos = atomicAdd(&curs[e], 1);
  permflat[prefix + pos] = r;
}

// ---------------------------------------------------------------------------
__global__ __launch_bounds__(256) void gather_rows(
    const bf16_t* __restrict__ H, const int* __restrict__ permflat,
    const float* __restrict__ s0g, const float* __restrict__ s1g,
    bf16_t* __restrict__ Hp, int* __restrict__ rowid,
    float* __restrict__ s0p, float* __restrict__ s1p) {
  const int w = threadIdx.x >> 6, lane = threadIdx.x & 63;
  const int p = blockIdx.x * 4 + w;
  const int r = permflat[p];
  if (lane == 0) {
    rowid[p] = r;
    s0p[p] = s0g[r];
    s1p[p] = s1g[r];
  }
  const bf16x8* src = (const bf16x8*)(H + (size_t)r * HID);
  bf16x8* dst = (bf16x8*)(Hp + (size_t)p * HID);
#pragma unroll
  for (int i = 0; i < 4; ++i) dst[lane + i * 64] = src[lane + i * 64];
}

// ---------------------------------------------------------------------------
// expert_gemm_t: contiguous-A expert GEMM over Hperm, tile table from cnt[].
// BK=64 + swizzled LDS. COL-FAST: grid (HID/128, 136); blockIdx.y = token
// tile (table lookup), blockIdx.x = col tile. mid[rowid] = s0*(h@We + be).
// ---------------------------------------------------------------------------
__global__ __launch_bounds__(256) void expert_gemm_t(
    const bf16_t* __restrict__ Hp, const bf16_t* __restrict__ wTall,
    size_t wstride, const float* __restrict__ expBf,
    const int* __restrict__ cnt, const int* __restrict__ rowid,
    const float* __restrict__ s0p, bf16_t* __restrict__ mid) {
  __shared__ bf16_t As[128 * 64];
  __shared__ bf16_t Bs[128 * 64];
  __shared__ int rows_s[128];
  __shared__ float s0_s[128];

  // tile table on the fly: y -> (expert e, tile t)
  const int x = blockIdx.y;  // token-tile index (slow dim)
  int e = -1, base = 0, nrows = 0;
  {
    int acc = 0, pre = 0;
    for (int ee = 0; ee < NEXP; ++ee) {
      const int ce = cnt[ee];
      const int nt = (ce + 127) >> 7;
      if (x < acc + nt) {
        const int t = x - acc;
        e = ee;
        base = pre + t * 128;
        nrows = ce - t * 128;
        if (nrows > 128) nrows = 128;
        break;
      }
      acc += nt;
      pre += ce;
    }
  }
  if (e < 0) return;

  const int tid = threadIdx.x, lane = tid & 63, w = tid >> 6;
  const int wr = w >> 1, wc = w & 1, quad = lane >> 4, l16 = lane & 15;

  if (tid < 128) {
    int grow = -1;
    float a0 = 0.f;
    if (tid < nrows) {
      grow = rowid[base + tid];
      a0 = s0p[base + tid];
    }
    rows_s[tid] = grow;
    s0_s[tid] = a0;
  }
  __syncthreads();

  const int n0 = blockIdx.x * 128;  // col tile (fast dim)
  const char* Hb = (const char*)Hp;
  const char* Wb = (const char*)(wTall + (size_t)e * wstride);

  size_t aoff[4], boff[4];
  int cb[4];
#pragma unroll
  for (int c = 0; c < 4; ++c) {
    cb[c] = (w * 4 + c) * 1024;
    const int o = cb[c] + lane * 16;
    const int row = o >> 7;
    const int kb = (o & 127) ^ ((row & 7) << 4);
    int ar = base + row;
    if (ar > N_TOK - 1) ar = N_TOK - 1;  // tail-tile clamp (masked at write)
    aoff[c] = (size_t)ar * (HID * 2) + kb;
    boff[c] = (size_t)(n0 + row) * (HID * 2) + kb;
  }
  const int sw = (l16 & 7) << 3;

  const f32x4 fz = {0.f, 0.f, 0.f, 0.f};
  f32x4 acc[4][4];
#pragma unroll
  for (int i = 0; i < 4; ++i)
#pragma unroll
    for (int j = 0; j < 4; ++j) acc[i][j] = fz;

  for (int kt = 0; kt < HID / 64; ++kt) {
    __syncthreads();
#pragma unroll
    for (int c = 0; c < 4; ++c) {
      ASYNC16(Hb + aoff[c] + (size_t)kt * 128, (char*)As + cb[c]);
      ASYNC16(Wb + boff[c] + (size_t)kt * 128, (char*)Bs + cb[c]);
    }
    __syncthreads();

#pragma unroll
    for (int ks = 0; ks < 2; ++ks) {
      const int co = (ks * 32 + quad * 8) ^ sw;
      bf16x8 af[4], bfr[4];
#pragma unroll
      for (int i = 0; i < 4; ++i)
        af[i] = *(const bf16x8*)&As[(wr * 64 + i * 16 + l16) * 64 + co];
#pragma unroll
      for (int j = 0; j < 4; ++j)
        bfr[j] = *(const bf16x8*)&Bs[(wc * 64 + j * 16 + l16) * 64 + co];
#pragma unroll
      for (int i = 0; i < 4; ++i)
#pragma unroll
        for (int j = 0; j < 4; ++j)
          acc[i][j] = __builtin_amdgcn_mfma_f32_16x16x32_bf16(
              af[i], bfr[j], acc[i][j], 0, 0, 0);
    }
  }

  const float* eBe = expBf + (size_t)e * HID;
  float beb[4];
  int colj[4];
#pragma unroll
  for (int j = 0; j < 4; ++j) {
    colj[j] = n0 + wc * 64 + j * 16 + l16;
    beb[j] = eBe[colj[j]];
  }
#pragma unroll
  for (int i = 0; i < 4; ++i) {
#pragma unroll
    for (int r = 0; r < 4; ++r) {
      const int lr = wr * 64 + i * 16 + quad * 4 + r;
      const int grow = rows_s[lr];
      if (grow < 0) continue;
      const float s0 = s0_s[lr];
#pragma unroll
      for (int j = 0; j < 4; ++j) {
        const float v = CLAMP1E4(s0 * (acc[i][j][r] + beb[j]));
        mid[(size_t)grow * HID + colj[j]] = (bf16_t)v;
      }
    }
  }
}

// ---------------------------------------------------------------------------
// res_gemm_p: reads Hperm (contiguous), RMW-scatters into mid[rowid].
// BK=64 + swizzled LDS. COL-FAST grid (HID/128, N_TOK/128).
// ---------------------------------------------------------------------------
__global__ __launch_bounds__(256) void res_gemm_p(
    const bf16_t* __restrict__ Hp, const bf16_t* __restrict__ Bt,
    const float* __restrict__ rB, const int* __restrict__ rowid,
    const float* __restrict__ s1p, bf16_t* __restrict__ mid) {
  __shared__ bf16_t As[128 * 64];
  __shared__ bf16_t Bs[128 * 64];

  const int tid = threadIdx.x, lane = tid & 63, w = tid >> 6;
  const int wr = w >> 1, wc = w & 1, quad = lane >> 4, l16 = lane & 15;
  const int m0 = blockIdx.y * 128, n0 = blockIdx.x * 128;  // col-fast
  const char* Ab = (const char*)Hp;
  const char* Bb = (const char*)Bt;

  size_t aoff[4], boff[4];
  int cb[4];
#pragma unroll
  for (int c = 0; c < 4; ++c) {
    cb[c] = (w * 4 + c) * 1024;
    const int o = cb[c] + lane * 16;
    const int row = o >> 7;
    const int kb = (o & 127) ^ ((row & 7) << 4);
    aoff[c] = (size_t)(m0 + row) * (HID * 2) + kb;
    boff[c] = (size_t)(n0 + row) * (HID * 2) + kb;
  }
  const int sw = (l16 & 7) << 3;

  const f32x4 fz = {0.f, 0.f, 0.f, 0.f};
  f32x4 acc[4][4];
#pragma unroll
  for (int i = 0; i < 4; ++i)
#pragma unroll
    for (int j = 0; j < 4; ++j) acc[i][j] = fz;

  for (int kt = 0; kt < HID / 64; ++kt) {
    __syncthreads();
#pragma unroll
    for (int c = 0; c < 4; ++c) {
      ASYNC16(Ab + aoff[c] + (size_t)kt * 128, (char*)As + cb[c]);
      ASYNC16(Bb + boff[c] + (size_t)kt * 128, (char*)Bs + cb[c]);
    }
    __syncthreads();

#pragma unroll
    for (int ks = 0; ks < 2; ++ks) {
      const int co = (ks * 32 + quad * 8) ^ sw;
      bf16x8 af[4], bfr[4];
#pragma unroll
      for (int i = 0; i < 4; ++i)
        af[i] = *(const bf16x8*)&As[(wr * 64 + i * 16 + l16) * 64 + co];
#pragma unroll
      for (int j = 0; j < 4; ++j)
        bfr[j] = *(const bf16x8*)&Bs[(wc * 64 + j * 16 + l16) * 64 + co];
#pragma unroll
      for (int i = 0; i < 4; ++i)
#pragma unroll
        for (int j = 0; j < 4; ++j)
          acc[i][j] = __builtin_amdgcn_mfma_f32_16x16x32_bf16(
              af[i], bfr[j], acc[i][j], 0, 0, 0);
    }
  }

  float rbb[4];
  int colj[4];
#pragma unroll
  for (int j = 0; j < 4; ++j) {
    colj[j] = n0 + wc * 64 + j * 16 + l16;
    rbb[j] = rB[colj[j]];
  }
#pragma unroll
  for (int i = 0; i < 4; ++i) {
#pragma unroll
    for (int r = 0; r < 4; ++r) {
      const int p = m0 + wr * 64 + i * 16 + quad * 4 + r;
      const int grow = rowid[p];
      const float s1 = s1p[p];
#pragma unroll
      for (int j = 0; j < 4; ++j) {
        const size_t ix = (size_t)grow * HID + colj[j];
        const float v =
            CLAMP1E4(s1 * (acc[i][j][r] + rbb[j]) + (float)mid[ix]);
        mid[ix] = (bf16_t)v;
      }
    }
  }
}

// ---------------------------------------------------------------------------
// dec: out = mid @ dec_W + dec_b; BK=64 + swizzled LDS; COL-FAST grid
// (IN_DIM/128, N_TOK/128); output dtype per flag.
// ---------------------------------------------------------------------------
__global__ __launch_bounds__(256) void dec_gemm(
    const bf16_t* __restrict__ A, const bf16_t* __restrict__ Bt,
    const float* __restrict__ bias, void* __restrict__ C,
    const int* __restrict__ flagp) {
  __shared__ bf16_t As[128 * 64];
  __shared__ bf16_t Bs[128 * 64];

  const int fl = *flagp;
  const int tid = threadIdx.x, lane = tid & 63, w = tid >> 6;
  const int wr = w >> 1, wc = w & 1, quad = lane >> 4, l16 = lane & 15;
  const int m0 = blockIdx.y * 128, n0 = blockIdx.x * 128;  // col-fast
  const char* Ab = (const char*)A;
  const char* Bb = (const char*)Bt;

  size_t aoff[4], boff[4];
  int cb[4];
#pragma unroll
  for (int c = 0; c < 4; ++c) {
    cb[c] = (w * 4 + c) * 1024;
    const int o = cb[c] + lane * 16;
    const int row = o >> 7;
    const int kb = (o & 127) ^ ((row & 7) << 4);
    aoff[c] = (size_t)(m0 + row) * (HID * 2) + kb;
    boff[c] = (size_t)(n0 + row) * (HID * 2) + kb;
  }
  const int sw = (l16 & 7) << 3;

  const f32x4 fz = {0.f, 0.f, 0.f, 0.f};
  f32x4 acc[4][4];
#pragma unroll
  for (int i = 0; i < 4; ++i)
#pragma unroll
    for (int j = 0; j < 4; ++j) acc[i][j] = fz;

  for (int kt = 0; kt < HID / 64; ++kt) {
    __syncthreads();
#pragma unroll
    for (int c = 0; c < 4; ++c) {
      ASYNC16(Ab + aoff[c] + (size_t)kt * 128, (char*)As + cb[c]);
      ASYNC16(Bb + boff[c] + (size_t)kt * 128, (char*)Bs + cb[c]);
    }
    __syncthreads();

#pragma unroll
    for (int ks = 0; ks < 2; ++ks) {
      const int co = (ks * 32 + quad * 8) ^ sw;
      bf16x8 af[4], bfr[4];
#pragma unroll
      for (int i = 0; i < 4; ++i)
        af[i] = *(const bf16x8*)&As[(wr * 64 + i * 16 + l16) * 64 + co];
#pragma unroll
      for (int j = 0; j < 4; ++j)
        bfr[j] = *(const bf16x8*)&Bs[(wc * 64 + j * 16 + l16) * 64 + co];
#pragma unroll
      for (int i = 0; i < 4; ++i)
#pragma unroll
        for (int j = 0; j < 4; ++j)
          acc[i][j] = __builtin_amdgcn_mfma_f32_16x16x32_bf16(
              af[i], bfr[j], acc[i][j], 0, 0, 0);
    }
  }

  float bb[4];
  int colj[4];
#pragma unroll
  for (int j = 0; j < 4; ++j) {
    colj[j] = n0 + wc * 64 + j * 16 + l16;
    bb[j] = bias[colj[j]];
  }
#pragma unroll
  for (int i = 0; i < 4; ++i) {
#pragma unroll
    for (int r = 0; r < 4; ++r) {
      const int row = m0 + wr * 64 + i * 16 + quad * 4 + r;
#pragma unroll
      for (int j = 0; j < 4; ++j) {
        const float v = CLAMP1E4(acc[i][j][r] + bb[j]);
        const size_t ix = (size_t)row * IN_DIM + colj[j];
        if (fl)
          ((float*)C)[ix] = v;
        else
          ((bf16_t*)C)[ix] = (bf16_t)v;
      }
    }
  }
}

// ---------------------------------------------------------------------------
// small-path fallbacks (BK=32, R1 behavior; used only if ws can't hold wTall)
// ---------------------------------------------------------------------------
__global__ __launch_bounds__(256) void bucket_rows(
    const int* __restrict__ eidx, int* __restrict__ curs,
    int* __restrict__ perm) {
  const int r = blockIdx.x * 256 + threadIdx.x;
  const int e = eidx[r];
  const int pos = atomicAdd(&curs[e], 1);
  perm[(size_t)e * N_TOK + pos] = r;
}

__global__ __launch_bounds__(256) void expert_gemm(
    const bf16_t* __restrict__ H, const bf16_t* __restrict__ wTe,
    const float* __restrict__ eBe, const int* __restrict__ permE,
    const int* __restrict__ cnt, int e, const float* __restrict__ s0g,
    bf16_t* __restrict__ mid) {
  __shared__ bf16_t As[128 * 32];
  __shared__ bf16_t Bs[128 * 32];
  __shared__ int rows_s[128];
  __shared__ float s0_s[128];

  const int cnte = cnt[e];
  const int lt = blockIdx.x;
  if (lt * 128 >= cnte) return;
  int nrows = cnte - lt * 128;
  if (nrows > 128) nrows = 128;

  const int tid = threadIdx.x, lane = tid & 63, w = tid >> 6;
  const int wr = w >> 1, wc = w & 1, quad = lane >> 4, l16 = lane & 15;

  if (tid < 128) {
    int grow = -1;
    float a0 = 0.f;
    if (tid < nrows) {
      grow = permE[lt * 128 + tid];
      a0 = s0g[grow];
    }
    rows_s[tid] = grow;
    s0_s[tid] = a0;
  }
  __syncthreads();

  const int n0 = blockIdx.y * 128;
  const char* Hb = (const char*)H;
  const char* Wb = (const char*)wTe;

  size_t aoff[2], boff[2];
  int cb[2];
#pragma unroll
  for (int c = 0; c < 2; ++c) {
    cb[c] = (w * 2 + c) * 1024;
    const int o = cb[c] + lane * 16;
    const int row = o >> 6, kb = o & 63;
    int gr = rows_s[row];
    if (gr < 0) gr = 0;
    aoff[c] = (size_t)gr * (HID * 2) + kb;
    boff[c] = (size_t)(n0 + row) * (HID * 2) + kb;
  }

  const f32x4 fz = {0.f, 0.f, 0.f, 0.f};
  f32x4 acc[4][4];
#pragma unroll
  for (int i = 0; i < 4; ++i)
#pragma unroll
    for (int j = 0; j < 4; ++j) acc[i][j] = fz;

  for (int kt = 0; kt < HID / 32; ++kt) {
    __syncthreads();
#pragma unroll
    for (int c = 0; c < 2; ++c) {
      ASYNC16(Hb + aoff[c] + (size_t)kt * 64, (char*)As + cb[c]);
      ASYNC16(Wb + boff[c] + (size_t)kt * 64, (char*)Bs + cb[c]);
    }
    __syncthreads();

    bf16x8 af[4], bfr[4];
#pragma unroll
    for (int i = 0; i < 4; ++i)
      af[i] = *(const bf16x8*)&As[(wr * 64 + i * 16 + l16) * 32 + quad * 8];
#pragma unroll
    for (int j = 0; j < 4; ++j)
      bfr[j] = *(const bf16x8*)&Bs[(wc * 64 + j * 16 + l16) * 32 + quad * 8];
#pragma unroll
    for (int i = 0; i < 4; ++i)
#pragma unroll
      for (int j = 0; j < 4; ++j)
        acc[i][j] = __builtin_amdgcn_mfma_f32_16x16x32_bf16(af[i], bfr[j],
                                                            acc[i][j], 0, 0, 0);
  }

  float beb[4];
  int colj[4];
#pragma unroll
  for (int j = 0; j < 4; ++j) {
    colj[j] = n0 + wc * 64 + j * 16 + l16;
    beb[j] = eBe[colj[j]];
  }
#pragma unroll
  for (int i = 0; i < 4; ++i) {
#pragma unroll
    for (int r = 0; r < 4; ++r) {
      const int lr = wr * 64 + i * 16 + quad * 4 + r;
      const int grow = rows_s[lr];
      if (grow < 0) continue;
      const float s0 = s0_s[lr];
#pragma unroll
      for (int j = 0; j < 4; ++j) {
        const float v = CLAMP1E4(s0 * (acc[i][j][r] + beb[j]));
        mid[(size_t)grow * HID + colj[j]] = (bf16_t)v;
      }
    }
  }
}

__global__ __launch_bounds__(256) void res_gemm(
    const bf16_t* __restrict__ H, const bf16_t* __restrict__ Bt,
    const float* __restrict__ rB, const float* __restrict__ s1g,
    bf16_t* __restrict__ mid) {
  __shared__ bf16_t As[128 * 32];
  __shared__ bf16_t Bs[128 * 32];

  const int tid = threadIdx.x, lane = tid & 63, w = tid >> 6;
  const int wr = w >> 1, wc = w & 1, quad = lane >> 4, l16 = lane & 15;
  const int m0 = blockIdx.x * 128, n0 = blockIdx.y * 128;
  const char* Ab = (const char*)H;
  const char* Bb = (const char*)Bt;

  size_t aoff[2], boff[2];
  int cb[2];
#pragma unroll
  for (int c = 0; c < 2; ++c) {
    cb[c] = (w * 2 + c) * 1024;
    const int o = cb[c] + lane * 16;
    const int row = o >> 6, kb = o & 63;
    aoff[c] = (size_t)(m0 + row) * (HID * 2) + kb;
    boff[c] = (size_t)(n0 + row) * (HID * 2) + kb;
  }

  const f32x4 fz = {0.f, 0.f, 0.f, 0.f};
  f32x4 acc[4][4];
#pragma unroll
  for (int i = 0; i < 4; ++i)
#pragma unroll
    for (int j = 0; j < 4; ++j) acc[i][j] = fz;

  for (int kt = 0; kt < HID / 32; ++kt) {
    __syncthreads();
#pragma unroll
    for (int c = 0; c < 2; ++c) {
      ASYNC16(Ab + aoff[c] + (size_t)kt * 64, (char*)As + cb[c]);
      ASYNC16(Bb + boff[c] + (size_t)kt * 64, (char*)Bs + cb[c]);
    }
    __syncthreads();

    bf16x8 af[4], bfr[4];
#pragma unroll
    for (int i = 0; i < 4; ++i)
      af[i] = *(const bf16x8*)&As[(wr * 64 + i * 16 + l16) * 32 + quad * 8];
#pragma unroll
    for (int j = 0; j < 4; ++j)
      bfr[j] = *(const bf16x8*)&Bs[(wc * 64 + j * 16 + l16) * 32 + quad * 8];
#pragma unroll
    for (int i = 0; i < 4; ++i)
#pragma unroll
      for (int j = 0; j < 4; ++j)
        acc[i][j] = __builtin_amdgcn_mfma_f32_16x16x32_bf16(af[i], bfr[j],
                                                            acc[i][j], 0, 0, 0);
  }

  float rbb[4];
  int colj[4];
#pragma unroll
  for (int j = 0; j < 4; ++j) {
    colj[j] = n0 + wc * 64 + j * 16 + l16;
    rbb[j] = rB[colj[j]];
  }
#pragma unroll
  for (int i = 0; i < 4; ++i) {
#pragma unroll
    for (int r = 0; r < 4; ++r) {
      const int row = m0 + wr * 64 + i * 16 + quad * 4 + r;
      const float s1 = s1g[row];
#pragma unroll
      for (int j = 0; j < 4; ++j) {
        const size_t ix = (size_t)row * HID + colj[j];
        const float v =
            CLAMP1E4(s1 * (acc[i][j][r] + rbb[j]) + (float)mid[ix]);
        mid[ix] = (bf16_t)v;
      }
    }
  }
}

// ---------------------------------------------------------------------------
extern "C" void kernel_launch(void* const* d_in, const int* in_sizes, int n_in,
                              void* d_out, int out_size, void* d_ws,
                              size_t ws_size, hipStream_t stream) {
  (void)in_sizes; (void)n_in;

  const void* x     = d_in[0];
  const void* encW  = d_in[1];
  const void* encB  = d_in[2];
  const void* gateW = d_in[3];
  const void* expW  = d_in[4];
  const void* expB  = d_in[5];
  const void* resW  = d_in[6];
  const void* resB  = d_in[7];
  const void* coefW = d_in[8];
  const void* coefB = d_in[9];
  const void* decW  = d_in[10];
  const void* decB  = d_in[11];

  // --- workspace layout: ~142MB base, +80MB wTall if available ---
  char* ws = (char*)d_ws;
  size_t o = 0;
  int*    flag  = (int*)(ws + o);    o += 256;
  int*    cnt   = (int*)(ws + o);    o += 256;   // cnt[0..7]; acnt@[8]; curs@[16..23]
  int*    acnt  = cnt + 8;
  int*    curs  = cnt + 16;
  float*  s0g   = (float*)(ws + o);  o += (size_t)N_TOK * 4;
  float*  s1g   = (float*)(ws + o);  o += (size_t)N_TOK * 4;
  float*  c0g   = (float*)(ws + o);  o += (size_t)N_TOK * 4;
  int*    eidx  = (int*)(ws + o);    o += (size_t)N_TOK * 4;
  int*    ambig = (int*)(ws + o);    o += (size_t)N_TOK * 4;
  int*    permfl= (int*)(ws + o);    o += (size_t)N_TOK * 4;
  int*    rowid = (int*)(ws + o);    o += (size_t)N_TOK * 4;
  float*  s0p   = (float*)(ws + o);  o += (size_t)N_TOK * 4;
  float*  s1p   = (float*)(ws + o);  o += (size_t)N_TOK * 4;
  int*    perm  = (int*)(ws + o);    o += (size_t)NEXP * N_TOK * 4;  // small path
  float*  encBf = (float*)(ws + o);  o += HID * 4;
  float*  expBf = (float*)(ws + o);  o += (size_t)NEXP * HID * 4;
  float*  resBf = (float*)(ws + o);  o += HID * 4;
  float*  decBf = (float*)(ws + o);  o += IN_DIM * 4;
  float*  coefBf= (float*)(ws + o);  o += 256;
  bf16_t* gWb   = (bf16_t*)(ws + o); o += (size_t)HID * 8 * 2;
  bf16_t* cWb   = (bf16_t*)(ws + o); o += (size_t)HID * 2 * 2;
  o = (o + 255) & ~(size_t)255;
  bf16_t* bufA  = (bf16_t*)(ws + o); o += (size_t)N_TOK * HID * 2;   // 64 MB
  bf16_t* bufB  = (bf16_t*)(ws + o); o += (size_t)N_TOK * HID * 2;   // 64 MB
  bf16_t* wT    = (bf16_t*)(ws + o); o += (size_t)HID * HID * 2;     // 8 MB
  const size_t needed_small = o;
  const size_t S = (size_t)HID * HID;  // elements per wTall slot
  bf16_t* wTall = (bf16_t*)(ws + o);   // slots 0..7 experts, 8 res, 9 dec
  const size_t needed_big = o + 10 * S * 2;                          // +80 MB

  // pglg (f64 rescue partials, 1024 rows x 32 slices x 8 experts = 2MB)
  // lives in bufB: free window between enc_gemm (xbf dead) and gather_rows
  // (big path) / expert_gemm mid writes (small path).
  double* pglg = (double*)bufB;

  // buffer roles:
  //  big:   xbf=bufB -> enc writes H=bufA -> [rescue pglg in bufB] ->
  //         gather writes Hperm=bufB -> expert writes mid=bufA -> res RMWs
  //         mid -> dec reads bufA
  //  small: xbf=bufB -> enc writes H=bufA -> [rescue pglg in bufB] ->
  //         experts write mid=bufB -> dec reads bufB
  bf16_t* hbuf  = bufA;
  bf16_t* xbf   = bufB;

  if (ws_size < needed_small) {
    const float v = (float)(ws_size >> 20);  // report budget in MB
    fill_bf16<<<dim3((out_size + 255) / 256), 256, 0, stream>>>(
        (bf16_t*)d_out, v, out_size);
    return;
  }
  const bool big = ws_size >= needed_big;

  detect_dtype<<<1, 256, 0, stream>>>((const ushort_t*)x, flag);
  hipMemsetAsync(cnt, 0, 256, stream);

  // --- normalize inputs ---
  cvt_to_bf16_x4<<<dim3(N_TOK * IN_DIM / 4 / 256), 256, 0, stream>>>(
      x, xbf, N_TOK * IN_DIM / 4, flag);
  cvt_small<<<dim3(64, 7), 256, 0, stream>>>(encB, expB, resB, decB, coefB,
                                             gateW, coefW, encBf, expBf, resBf,
                                             decBf, coefBf, gWb, cWb, flag);

  const dim3 tb(32, 8, 1);

  // --- weight prep ---
  transpose_cvt<<<dim3(HID / 32, IN_DIM / 32, 1), tb, 0, stream>>>(
      encW, (ushort_t*)wT, IN_DIM, HID, 0, flag, 0, 0);
  if (big) {
    transpose_cvt<<<dim3(HID / 32, HID / 32, NEXP), tb, 0, stream>>>(
        expW, (ushort_t*)wTall, HID, HID, 0, flag, S, S);
    transpose_cvt<<<dim3(HID / 32, HID / 32, 1), tb, 0, stream>>>(
        resW, (ushort_t*)(wTall + 8 * S), HID, HID, 0, flag, 0, 0);
    transpose_cvt<<<dim3(IN_DIM / 32, HID / 32, 1), tb, 0, stream>>>(
        decW, (ushort_t*)(wTall + 9 * S), HID, IN_DIM, 0, flag, 0, 0);
  }

  // --- enc + gating (col-fast grids) ---
  enc_gemm<<<dim3(HID / 128, N_TOK / 128), 256, 0, stream>>>(xbf, wT, encBf,
                                                             hbuf);
  gate_from_h<<<dim3(N_TOK / 16), 256, 0, stream>>>(
      hbuf, gWb, cWb, coefBf, s0g, s1g, c0g, eidx, ambig, acnt, cnt);
  // tiled f64 rescue: 8 rows x 64 cols x 4 k-quarters per block, fixed-order
  rescue_tile2<<<dim3(128, 32), 256, 0, stream>>>(x, encW, encBf, gateW, flag,
                                                  ambig, acnt, pglg);
  rescue_final<<<dim3(1024), 64, 0, stream>>>(ambig, acnt, c0g, pglg, s0g,
                                              eidx, cnt);
  // overflow guard for acnt > 1024 (whole-row legacy path; normally no-op)
  rescue_rows<<<dim3(N_TOK - 1024), 256, 0, stream>>>(
      x, encW, encBf, gateW, flag, ambig, acnt, c0g, s0g, eidx, cnt, 1024);

  if (big) {
    bf16_t* Hperm = bufB;  // pglg consumed by rescue_final before gather
    bf16_t* mid   = bufA;  // H dead after gather
    place_rows<<<dim3(N_TOK / 256), 256, 0, stream>>>(eidx, cnt, curs, permfl);
    gather_rows<<<dim3(N_TOK / 4), 256, 0, stream>>>(hbuf, permfl, s0g, s1g,
                                                     Hperm, rowid, s0p, s1p);
    expert_gemm_t<<<dim3(HID / 128, 136), 256, 0, stream>>>(
        Hperm, wTall, S, expBf, cnt, rowid, s0p, mid);
    res_gemm_p<<<dim3(HID / 128, N_TOK / 128), 256, 0, stream>>>(
        Hperm, wTall + 8 * S, resBf, rowid, s1p, mid);
    dec_gemm<<<dim3(IN_DIM / 128, N_TOK / 128), 256, 0, stream>>>(
        mid, wTall + 9 * S, decBf, d_out, flag);
  } else {
    // --- fallback: serial per-expert path (R1 behavior) ---
    bf16_t* mid = bufB;  // pglg consumed before expert writes
    bucket_rows<<<dim3(N_TOK / 256), 256, 0, stream>>>(eidx, curs, perm);
    for (int e = 0; e < NEXP; ++e) {
      transpose_cvt<<<dim3(HID / 32, HID / 32, 1), tb, 0, stream>>>(
          expW, (ushort_t*)wT, HID, HID, (size_t)e * HID * HID, flag, 0, 0);
      expert_gemm<<<dim3(N_TOK / 128, HID / 128), 256, 0, stream>>>(
          hbuf, wT, expBf + (size_t)e * HID, perm + (size_t)e * N_TOK, cnt, e,
          s0g, mid);
    }
    transpose_cvt<<<dim3(HID / 32, HID / 32, 1), tb, 0, stream>>>(
        resW, (ushort_t*)wT, HID, HID, 0, flag, 0, 0);
    res_gemm<<<dim3(N_TOK / 128, HID / 128), 256, 0, stream>>>(hbuf, wT, resBf,
                                                               s1g, mid);
    transpose_cvt<<<dim3(IN_DIM / 32, HID / 32, 1), tb, 0, stream>>>(
        decW, (ushort_t*)wT, HID, IN_DIM, 0, flag, 0, 0);
    dec_gemm<<<dim3(N_TOK / 128, IN_DIM / 128), 256, 0, stream>>>(
        mid, wT, decBf, d_out, flag);
  }
}